// Round 12
// baseline (138.211 us; speedup 1.0000x reference)
//
#include <hip/hip_runtime.h>
#include <math.h>

#define NN   512
#define NCHQ 4       // chunks per block; each chunk = 32 receivers x 2 senders

#define C1 0.06154574548966636f   // 1/sqrt(264)
#define C2 0.08838834764831845f   // 1/sqrt(128)
#define SQRT3 1.7320508075688772f

typedef __attribute__((ext_vector_type(8))) short bf16x8;   // 8 bf16 = 4 VGPRs
typedef __attribute__((ext_vector_type(4))) float f32x4;

#define MFMA16 __builtin_amdgcn_mfma_f32_16x16x32_bf16
#define CVT_PK(dst, a, b) asm("v_cvt_pk_bf16_f32 %0, %1, %2" : "=v"(dst) : "v"(a), "v"(b))

__device__ __forceinline__ float silu_f(float x) {
    float e = __builtin_amdgcn_exp2f(x * -1.442695041f);
    return x * __builtin_amdgcn_rcpf(1.0f + e);
}
__device__ __forceinline__ float sigm_f(float x) {
    float e = __builtin_amdgcn_exp2f(x * -1.442695041f);
    return __builtin_amdgcn_rcpf(1.0f + e);
}
__device__ __forceinline__ short f2bf(float f) {
    unsigned u = __builtin_bit_cast(unsigned, f);
    u = (u + 0x7FFFu + ((u >> 16) & 1u)) >> 16;
    return (short)u;
}
__device__ __forceinline__ float bfhi(unsigned u) {
    return __builtin_bit_cast(float, u & 0xFFFF0000u);
}
__device__ __forceinline__ float bflo(unsigned u) {
    return __builtin_bit_cast(float, u << 16);
}

// ---------------------------------------------------------------------------
// k_packall: all weight packing + proj in ONE launch; weights PRE-SCALED.
// Frag (ct,kt), lane l, elem j holds W[32kt + (l>>4)*8 + j][16ct + (l&15)].
// ---------------------------------------------------------------------------
__device__ __forceinline__ void packW(const float* __restrict__ W,
                                      short* __restrict__ out, int ncols, int ct,
                                      float scale)
{
    int t = threadIdx.x;
    int lane = t & 63, kt = (t >> 6) & 3;
    int g = lane >> 4, c = lane & 15;
    bf16x8 v;
    #pragma unroll
    for (int j = 0; j < 8; ++j)
        v[j] = f2bf(W[(kt * 32 + g * 8 + j) * ncols + ct * 16 + c] * scale);
    *(bf16x8*)(out + (size_t)(ct * 256 + t) * 8) = v;
}

__global__ __launch_bounds__(256)
void k_packall(const float* __restrict__ We2, const float* __restrict__ Wx1,
               const float* __restrict__ Wx2, const float* __restrict__ Wtp,
               const float* __restrict__ We1, const float* __restrict__ feat,
               short* __restrict__ We2p, short* __restrict__ Wx1p,
               short* __restrict__ Wx2p, short* __restrict__ Wtpp,
               short* __restrict__ We1Lp,
               float* __restrict__ FsP, float* __restrict__ FrP)
{
    const int b = blockIdx.x, t = threadIdx.x;
    if (b < 8)  { packW(We2, We2p, 128, b,      C2);       return; }
    if (b < 16) { packW(Wx1, Wx1p, 128, b - 8,  C2);       return; }
    if (b < 24) { packW(Wx2, Wx2p, 128, b - 16, C2);       return; }
    if (b < 28) { packW(Wtp, Wtpp,  64, b - 24, 0.03125f); return; } // 1/sqrt(U*V)
    if (b == 28) {
        #pragma unroll
        for (int h = 0; h < 2; ++h) {
            int tt = t + h * 256;
            int ct = tt >> 6, l = tt & 63, g = l >> 4, c = l & 15;
            bf16x8 v = {0,0,0,0,0,0,0,0};
            if (g == 0) {
                #pragma unroll
                for (int j = 0; j < 8; ++j)
                    v[j] = f2bf(We1[j * 128 + ct * 16 + c] * C1);
            }
            *(bf16x8*)(We1Lp + (size_t)tt * 8) = v;
        }
        return;
    }
    __shared__ float sF[256];
    const int n = (b - 29) * 2 + (t >> 7), j = t & 127, hb = t & 128;
    sF[t] = feat[n * 128 + j];
    __syncthreads();
    float a = 0.f, bb = 0.f;
    #pragma unroll 8
    for (int k = 0; k < 128; ++k) {
        float f = sF[hb + k];
        a  = fmaf(f, We1[(8   + k) * 128 + j], a);
        bb = fmaf(f, We1[(136 + k) * 128 + j], bb);
    }
    FsP[n * 128 + j] = a * C1;
    FrP[n * 128 + j] = bb * C1;
}

// ---------------------------------------------------------------------------
__device__ __forceinline__ void loadBz(const short* __restrict__ p,
                                       bf16x8 (&B)[2][4], int w, int lane)
{
    int zz = 0; asm volatile("" : "+v"(zz));
    const bf16x8* p8 = (const bf16x8*)p;
    #pragma unroll
    for (int ctl = 0; ctl < 2; ++ctl)
        #pragma unroll
        for (int kt = 0; kt < 4; ++kt)
            B[ctl][kt] = p8[((w * 2 + ctl) * 4 + kt) * 64 + lane + zz];
}

// 64-row x 32-col (per wave) GEMM over K=128 from swizzled LDS
__device__ __forceinline__ void gemm64(const short* sIn_, const bf16x8 (&B)[2][4],
                                       const int (&adrK)[4], f32x4 (&acc)[4][2])
{
    const char* sIn = (const char*)sIn_;
    const f32x4 z = {0.f, 0.f, 0.f, 0.f};
    #pragma unroll
    for (int f = 0; f < 4; ++f) { acc[f][0] = z; acc[f][1] = z; }
    __builtin_amdgcn_s_setprio(1);
    #pragma unroll
    for (int f = 0; f < 4; ++f)
        #pragma unroll
        for (int kt = 0; kt < 4; ++kt) {
            bf16x8 a = *(const bf16x8*)(sIn + adrK[kt] + f * 4096);
            acc[f][0] = MFMA16(a, B[0][kt], acc[f][0], 0, 0, 0);
            acc[f][1] = MFMA16(a, B[1][kt], acc[f][1], 0, 0, 0);
        }
    __builtin_amdgcn_s_setprio(0);
}

// epilogue: pure silu -> cvt_pk -> b16 scatter; optional packed keep (bf16 pairs)
template<bool KEEP>
__device__ __forceinline__ void epi64(const f32x4 (&acc)[4][2], short* sOut_,
                                      const int (&wAdr)[2][4],
                                      unsigned (&keep)[4][2][2])
{
    char* sOut = (char*)sOut_;
    #pragma unroll
    for (int f = 0; f < 4; ++f)
        #pragma unroll
        for (int ctl = 0; ctl < 2; ++ctl) {
            float v0 = silu_f(acc[f][ctl][0]);
            float v1 = silu_f(acc[f][ctl][1]);
            float v2 = silu_f(acc[f][ctl][2]);
            float v3 = silu_f(acc[f][ctl][3]);
            unsigned p01, p23;
            CVT_PK(p01, v0, v1);
            CVT_PK(p23, v2, v3);
            if (KEEP) { keep[f][ctl][0] = p01; keep[f][ctl][1] = p23; }
            char* o = sOut + f * 4096;
            *(short*)(o + wAdr[ctl][0]) = (short)(p01 & 0xFFFFu);
            *(short*)(o + wAdr[ctl][1]) = (short)(p01 >> 16);
            *(short*)(o + wAdr[ctl][2]) = (short)(p23 & 0xFFFFu);
            *(short*)(o + wAdr[ctl][3]) = (short)(p23 >> 16);
        }
}

// ---------------------------------------------------------------------------
// k_edge: one block per (sender-PAIR, receiver-quarter). Each chunk processes
// 32 receivers x 2 senders = 64 rows (rows 0-31: sender A, 32-63: sender B).
// FrP / pos receiver reads shared across the pair; weight loads amortized 2x.
// ---------------------------------------------------------------------------
__global__ __launch_bounds__(256, 4)
void k_edge(const float* __restrict__ pos,
            const float* __restrict__ Winf,
            const float* __restrict__ FsP,
            const float* __restrict__ FrP,
            const short* __restrict__ We1Lp,
            const short* __restrict__ We2p,
            const short* __restrict__ Wx1p,
            const short* __restrict__ Wx2p,
            const short* __restrict__ Wtpp,
            float* __restrict__ MIq,
            float* __restrict__ VECq)
{
    __shared__ __align__(16) short sX[64 * 128];        // 16KB bf16, swizzled
    __shared__ __align__(16) short sY[64 * 128];        // 16KB
    __shared__ __align__(8)  unsigned sLS[64 * 8 * 2];  // 4KB: bf16x4 (sh.xyz,len)/slot
    __shared__ float sWinf[8 * 17];
    __shared__ float sPosS[48];                         // both senders
    __shared__ float sE[64];
    __shared__ float sVp[4 * 48];

    const int bid = blockIdx.x;
    const int pair = bid >> 2, q = bid & 3;
    const int sA = pair * 2, sB = sA + 1;
    const int t = threadIdx.x;
    const int lane = t & 63, w = t >> 6;
    const int rl = lane & 15, kg = lane >> 4;

    // ---- per-thread constant LDS byte addresses (frag f adds f*4096) ----
    const int swz = (rl & 7) << 4;
    const int ktperm = (rl & 4) << 4;
    const int baseRd = rl * 256 + ((kg * 16) ^ (swz & 0x30));
    int adrK[4];
    #pragma unroll
    for (int kt = 0; kt < 4; ++kt) adrK[kt] = baseRd + ((kt * 64) ^ ktperm);
    int wAdr[2][4];
    #pragma unroll
    for (int ctl = 0; ctl < 2; ++ctl)
        #pragma unroll
        for (int jj = 0; jj < 4; ++jj) {
            int r = kg * 4 + jj;
            wAdr[ctl][jj] = r * 256 + ((w * 64 + ctl * 32 + 2 * rl) ^ ((r & 7) << 4));
        }
    const int colg0 = w * 32 + rl, colg1 = colg0 + 16;
    // e-phase: 4 threads per row, each covering 32 cols
    const int erow = t >> 2, eseg = t & 3;
    int eAdr[4];
    #pragma unroll
    for (int k = 0; k < 4; ++k)
        eAdr[k] = erow * 256 + ((eseg * 64 + k * 16) ^ ((erow & 7) << 4));
    const int vv = w * 2 + (rl >> 3);

    if (t < 128) sWinf[(t >> 4) * 17 + (t & 15)] = Winf[t];
    if (t < 48)  sPosS[t] = pos[sA * 24 + t];   // sB = sA+1 -> contiguous

    const float fsA0 = FsP[sA * 128 + colg0], fsA1 = FsP[sA * 128 + colg1];
    const float fsB0 = FsP[sB * 128 + colg0], fsB1 = FsP[sB * 128 + colg1];

    float miA0 = 0.f, miA1 = 0.f, miB0 = 0.f, miB1 = 0.f;
    float vA0 = 0.f, vA1 = 0.f, vA2 = 0.f, vB0 = 0.f, vB1 = 0.f, vB2 = 0.f;
    __syncthreads();                                              // B0

    for (int c = 0; c < NCHQ; ++c) {
        const int r0 = q * 128 + c * 32;

        // ==== chunk-top: We1L frags + shared FrP (rows reused by both senders) ====
        bf16x8 bL0, bL1;
        {
            int zz = 0; asm volatile("" : "+v"(zz));
            const bf16x8* pL = (const bf16x8*)We1Lp;
            bL0 = pL[(w * 2 + 0) * 64 + lane + zz];
            bL1 = pL[(w * 2 + 1) * 64 + lane + zz];
        }
        float frv[2][2][4];
        {
            int zz = 0; asm volatile("" : "+v"(zz));
            #pragma unroll
            for (int rt = 0; rt < 2; ++rt)
                #pragma unroll
                for (int jj = 0; jj < 4; ++jj) {
                    const float* fp = FrP + (size_t)(r0 + rt * 16 + kg * 4 + jj) * 128 + zz;
                    frv[rt][0][jj] = fp[colg0];
                    frv[rt][1][jj] = fp[colg1];
                }
        }

        // ---- ph0: lengths + sh1 for BOTH senders (shared receiver read) ----
        {
            int r = t >> 3, v = t & 7;
            const float* pr = pos + (size_t)(r0 + r) * 24 + v * 3;
            float px = pr[0], py = pr[1], pz = pr[2];
            int slot = (r * 8 + (v ^ (r & 7))) * 2;       // u32 units
            #pragma unroll
            for (int sidx = 0; sidx < 2; ++sidx) {
                float dx = sPosS[sidx * 24 + v * 3 + 0] - px;
                float dy = sPosS[sidx * 24 + v * 3 + 1] - py;
                float dz = sPosS[sidx * 24 + v * 3 + 2] - pz;
                float sq = fmaxf(dx * dx + dy * dy + dz * dz, 1e-20f);
                float rs = __builtin_amdgcn_rsqf(sq);
                float len = sq * rs;
                float inv = SQRT3 * rs;
                unsigned lo, hi;
                CVT_PK(lo, dx * inv, dy * inv);
                CVT_PK(hi, dz * inv, len);
                sLS[slot + sidx * 512]     = lo;
                sLS[slot + sidx * 512 + 1] = hi;
            }
        }
        __syncthreads();                                          // B1

        // ---- L1: lens @ We1L' with C = fr'+fs'; silu -> sX ----
        {
            bf16x8 aL[4];
            #pragma unroll
            for (int f = 0; f < 4; ++f) {
                bf16x8 zv = {0,0,0,0,0,0,0,0};
                aL[f] = zv;
            }
            if (kg == 0) {
                #pragma unroll
                for (int f = 0; f < 4; ++f)
                    #pragma unroll
                    for (int j = 0; j < 8; ++j)
                        aL[f][j] = *(const short*)((const char*)sLS +
                            (((f * 16 + rl) * 8 + (j ^ (rl & 7))) * 8 + 6));
            }
            f32x4 aP[4][2];
            __builtin_amdgcn_s_setprio(1);
            #pragma unroll
            for (int f = 0; f < 4; ++f) {
                float fs0 = (f < 2) ? fsA0 : fsB0;
                float fs1 = (f < 2) ? fsA1 : fsB1;
                f32x4 c0, c1;
                #pragma unroll
                for (int jj = 0; jj < 4; ++jj) {
                    c0[jj] = frv[f & 1][0][jj] + fs0;
                    c1[jj] = frv[f & 1][1][jj] + fs1;
                }
                aP[f][0] = MFMA16(aL[f], bL0, c0, 0, 0, 0);
                aP[f][1] = MFMA16(aL[f], bL1, c1, 0, 0, 0);
            }
            __builtin_amdgcn_s_setprio(0);
            bf16x8 Bw0[2][4];
            loadBz(We2p, Bw0, w, lane);            // We2 in flight under L1 epi
            unsigned dummy[4][2][2];
            epi64<false>(aP, sX, wAdr, dummy);
            __syncthreads();                                      // B2

            // ---- L2: m = silu(a1 @ We2') -> sY ; keep packed bf16 ----
            f32x4 acc[4][2];
            unsigned keep[4][2][2];
            gemm64(sX, Bw0, adrK, acc);
            bf16x8 Bn[2][4];
            loadBz(Wx1p, Bn, w, lane);             // Wx1 in flight
            epi64<true>(acc, sY, wAdr, keep);
            __syncthreads();                                      // B3

            // ---- e-phase (reads sY; sE write covered by B5) ----
            {
                float d = 0.f;
                #pragma unroll
                for (int k = 0; k < 4; ++k) {
                    uint4 m = *(const uint4*)((const char*)sY + eAdr[k]);
                    const unsigned mu[4] = {m.x, m.y, m.z, m.w};
                    const float* wf = sWinf + (eseg * 2 + (k >> 1)) * 17 + (k & 1) * 8;
                    #pragma unroll
                    for (int i = 0; i < 4; ++i) {
                        d = fmaf(bflo(mu[i]), wf[2 * i],     d);
                        d = fmaf(bfhi(mu[i]), wf[2 * i + 1], d);
                    }
                }
                d += __shfl_xor(d, 1); d += __shfl_xor(d, 2);
                if ((t & 3) == 0) {
                    int recv = r0 + (erow & 31);
                    int snd = (erow < 32) ? sA : sB;
                    sE[erow] = (recv == snd) ? 0.f : sigm_f(d * C2);
                }
            }

            // ---- L3: phi1 ; Wx2 in flight under epi ----
            gemm64(sY, Bn, adrK, acc);
            loadBz(Wx2p, Bw0, w, lane);
            epi64<false>(acc, sX, wAdr, dummy);
            __syncthreads();                                      // B5

            // ---- m_i accumulation (packed keep + sE) ----
            #pragma unroll
            for (int f = 0; f < 4; ++f)
                #pragma unroll
                for (int jj = 0; jj < 4; ++jj) {
                    float e = sE[f * 16 + kg * 4 + jj];
                    unsigned k0 = keep[f][0][jj >> 1];
                    unsigned k1 = keep[f][1][jj >> 1];
                    float m0 = (jj & 1) ? bfhi(k0) : bflo(k0);
                    float m1 = (jj & 1) ? bfhi(k1) : bflo(k1);
                    if (f < 2) { miA0 = fmaf(m0, e, miA0); miA1 = fmaf(m1, e, miA1); }
                    else       { miB0 = fmaf(m0, e, miB0); miB1 = fmaf(m1, e, miB1); }
                }

            // ---- L4: phi2 ; Wtp in flight under epi ----
            gemm64(sX, Bw0, adrK, acc);
            bf16x8 Bt[4];
            {
                int zz = 0; asm volatile("" : "+v"(zz));
                const bf16x8* p8 = (const bf16x8*)Wtpp;
                #pragma unroll
                for (int kt = 0; kt < 4; ++kt) Bt[kt] = p8[(w * 4 + kt) * 64 + lane + zz];
            }
            epi64<false>(acc, sY, wAdr, dummy);
            __syncthreads();                                      // B6

            // ---- TP gemm (Wtp' includes 1/32) + vec acc from sLS ----
            {
                const f32x4 z = {0.f, 0.f, 0.f, 0.f};
                f32x4 a4[4] = {z, z, z, z};
                const char* sYc = (const char*)sY;
                __builtin_amdgcn_s_setprio(1);
                #pragma unroll
                for (int f = 0; f < 4; ++f)
                    #pragma unroll
                    for (int kt = 0; kt < 4; ++kt) {
                        bf16x8 a = *(const bf16x8*)(sYc + adrK[kt] + f * 4096);
                        a4[f] = MFMA16(a, Bt[kt], a4[f], 0, 0, 0);
                    }
                __builtin_amdgcn_s_setprio(0);
                #pragma unroll
                for (int f = 0; f < 4; ++f)
                    #pragma unroll
                    for (int jj = 0; jj < 4; ++jj) {
                        int row = f * 16 + kg * 4 + jj;
                        int sl = (row * 8 + (vv ^ (row & 7))) * 2;
                        unsigned lo = sLS[sl], hi = sLS[sl + 1];
                        float g = a4[f][jj];
                        if (f < 2) {
                            vA0 = fmaf(g, bflo(lo), vA0);
                            vA1 = fmaf(g, bfhi(lo), vA1);
                            vA2 = fmaf(g, bflo(hi), vA2);
                        } else {
                            vB0 = fmaf(g, bflo(lo), vB0);
                            vB1 = fmaf(g, bfhi(lo), vB1);
                            vB2 = fmaf(g, bflo(hi), vB2);
                        }
                    }
            }
            __syncthreads();                                      // B7 (sLS reuse)
        }
    }

    // ---- epilogue: m_i reduce over kg groups ----
    miA0 += __shfl_xor(miA0, 16); miA0 += __shfl_xor(miA0, 32);
    miA1 += __shfl_xor(miA1, 16); miA1 += __shfl_xor(miA1, 32);
    miB0 += __shfl_xor(miB0, 16); miB0 += __shfl_xor(miB0, 32);
    miB1 += __shfl_xor(miB1, 16); miB1 += __shfl_xor(miB1, 32);
    if (lane < 16) {
        float* moA = MIq + ((size_t)q * NN + sA) * 128;
        float* moB = MIq + ((size_t)q * NN + sB) * 128;
        moA[w * 32 + rl]      = miA0;
        moA[w * 32 + 16 + rl] = miA1;
        moB[w * 32 + rl]      = miB0;
        moB[w * 32 + 16 + rl] = miB1;
    }
    // ---- vec reduce (sum over v and kg; w_out = lane&7 survives) ----
    vA0 += __shfl_xor(vA0, 8);  vA1 += __shfl_xor(vA1, 8);  vA2 += __shfl_xor(vA2, 8);
    vA0 += __shfl_xor(vA0, 16); vA1 += __shfl_xor(vA1, 16); vA2 += __shfl_xor(vA2, 16);
    vA0 += __shfl_xor(vA0, 32); vA1 += __shfl_xor(vA1, 32); vA2 += __shfl_xor(vA2, 32);
    vB0 += __shfl_xor(vB0, 8);  vB1 += __shfl_xor(vB1, 8);  vB2 += __shfl_xor(vB2, 8);
    vB0 += __shfl_xor(vB0, 16); vB1 += __shfl_xor(vB1, 16); vB2 += __shfl_xor(vB2, 16);
    vB0 += __shfl_xor(vB0, 32); vB1 += __shfl_xor(vB1, 32); vB2 += __shfl_xor(vB2, 32);
    if ((lane & 56) == 0) {
        float* vp = sVp + w * 48 + lane * 3;
        vp[0] = vA0; vp[1] = vA1; vp[2] = vA2;
        vp[24] = vB0; vp[25] = vB1; vp[26] = vB2;
    }
    __syncthreads();
    if (t < 48) {
        int sidx = t / 24, comp = t % 24;
        float sum = sVp[sidx * 24 + comp] + sVp[48 + sidx * 24 + comp]
                  + sVp[96 + sidx * 24 + comp] + sVp[144 + sidx * 24 + comp];
        VECq[((size_t)q * NN + sA + sidx) * 24 + comp] = sum;
    }
}

// ---------------------------------------------------------------------------
// k_node: per-node h-MLP + residual + position update (sums 4 quarters).
// ---------------------------------------------------------------------------
__global__ __launch_bounds__(128)
void k_node(const float* __restrict__ pos, const float* __restrict__ feat,
            const float* __restrict__ Wh1, const float* __restrict__ Wh2,
            const float* __restrict__ Wh3,
            const float* __restrict__ MIq, const float* __restrict__ VECq,
            float* __restrict__ outPos, float* __restrict__ outFeat)
{
    __shared__ float sMi[128], sF[128], sH[128];
    int n = blockIdx.x, j = threadIdx.x;
    sMi[j] = MIq[n * 128 + j] + MIq[(NN + n) * 128 + j]
           + MIq[(2 * NN + n) * 128 + j] + MIq[(3 * NN + n) * 128 + j];
    sF[j]  = feat[n * 128 + j];
    __syncthreads();
    float a = 0.f;
    #pragma unroll 8
    for (int k = 0; k < 128; ++k) a = fmaf(sMi[k], Wh1[k * 128 + j], a);
    #pragma unroll 8
    for (int k = 0; k < 128; ++k) a = fmaf(sF[k], Wh1[(128 + k) * 128 + j], a);
    a = silu_f(a * 0.0625f);            // 1/sqrt(256)
    sH[j] = a;
    __syncthreads();
    float b = 0.f;
    #pragma unroll 8
    for (int k = 0; k < 128; ++k) b = fmaf(sH[k], Wh2[k * 128 + j], b);
    b = silu_f(b * C2);
    sMi[j] = b;
    __syncthreads();
    float cc = 0.f;
    #pragma unroll 8
    for (int k = 0; k < 128; ++k) cc = fmaf(sMi[k], Wh3[k * 128 + j], cc);
    outFeat[n * 128 + j] = cc * C2 + sF[j];
    if (j < 24) outPos[n * 24 + j] = pos[n * 24 + j]
                                   + VECq[n * 24 + j] + VECq[(NN + n) * 24 + j]
                                   + VECq[(2 * NN + n) * 24 + j]
                                   + VECq[(3 * NN + n) * 24 + j];
}

// ---------------------------------------------------------------------------
extern "C" void kernel_launch(void* const* d_in, const int* in_sizes, int n_in,
                              void* d_out, int out_size, void* d_ws, size_t ws_size,
                              hipStream_t stream) {
    const float* pos  = (const float*)d_in[0];
    const float* feat = (const float*)d_in[1];
    const float* We1  = (const float*)d_in[2];
    const float* We2  = (const float*)d_in[3];
    const float* Wx1  = (const float*)d_in[4];
    const float* Wx2  = (const float*)d_in[5];
    const float* Winf = (const float*)d_in[6];
    const float* Wtp  = (const float*)d_in[7];
    const float* Wh1  = (const float*)d_in[8];
    const float* Wh2  = (const float*)d_in[9];
    const float* Wh3  = (const float*)d_in[10];

    float* outPos  = (float*)d_out;              // [512*8*3]
    float* outFeat = (float*)d_out + NN * 24;    // [512*128]

    float* ws   = (float*)d_ws;
    float* FsP  = ws;                   // 65536 floats (pre-scaled C1)
    float* FrP  = ws + 65536;           // 65536 (pre-scaled C1)
    float* MIq  = ws + 131072;          // 4*65536
    float* VECq = ws + 393216;          // 4*12288
    short* wpack = (short*)(ws + 442368);
    short* We2p  = wpack;               // 16384 shorts (pre-scaled C2)
    short* Wx1p  = wpack + 16384;       // 16384 (C2)
    short* Wx2p  = wpack + 32768;       // 16384 (C2)
    short* Wtpp  = wpack + 49152;       // 8192  (1/32)
    short* We1Lp = wpack + 57344;       // 4096  (C1)

    k_packall<<<dim3(285), dim3(256), 0, stream>>>(We2, Wx1, Wx2, Wtp, We1, feat,
                                                   We2p, Wx1p, Wx2p, Wtpp, We1Lp,
                                                   FsP, FrP);
    k_edge<<<dim3(4 * 256), dim3(256), 0, stream>>>(pos, Winf, FsP, FrP, We1Lp,
                                                    We2p, Wx1p, Wx2p, Wtpp, MIq, VECq);
    k_node<<<dim3(NN), dim3(128), 0, stream>>>(pos, feat, Wh1, Wh2, Wh3, MIq, VECq,
                                               outPos, outFeat);
}

// Round 13
// 128.164 us; speedup vs baseline: 1.0784x; 1.0784x over previous
//
#include <hip/hip_runtime.h>
#include <math.h>

#define NN   512
#define NV   8
#define CH   32      // receivers per chunk
#define NCHH 8       // chunks per half-block (2 blocks per sender)

#define C1 0.06154574548966636f   // 1/sqrt(264)
#define C2 0.08838834764831845f   // 1/sqrt(128)
#define SQRT3 1.7320508075688772f

typedef __attribute__((ext_vector_type(8))) short bf16x8;   // 8 bf16 = 4 VGPRs
typedef __attribute__((ext_vector_type(4))) float f32x4;

#define MFMA16 __builtin_amdgcn_mfma_f32_16x16x32_bf16
#define CVT_PK(dst, a, b) asm("v_cvt_pk_bf16_f32 %0, %1, %2" : "=v"(dst) : "v"(a), "v"(b))

__device__ __forceinline__ float silu_f(float x) {
    float e = __builtin_amdgcn_exp2f(x * -1.442695041f);
    return x * __builtin_amdgcn_rcpf(1.0f + e);
}
__device__ __forceinline__ float sigm_f(float x) {
    float e = __builtin_amdgcn_exp2f(x * -1.442695041f);
    return __builtin_amdgcn_rcpf(1.0f + e);
}
__device__ __forceinline__ short f2bf(float f) {
    unsigned u = __builtin_bit_cast(unsigned, f);
    u = (u + 0x7FFFu + ((u >> 16) & 1u)) >> 16;
    return (short)u;
}
__device__ __forceinline__ float bfhi(unsigned u) {
    return __builtin_bit_cast(float, u & 0xFFFF0000u);
}
__device__ __forceinline__ float bflo(unsigned u) {
    return __builtin_bit_cast(float, u << 16);
}

// ---------------------------------------------------------------------------
// k_packall: all weight packing + proj in ONE launch; weights PRE-SCALED.
// Frag (ct,kt), lane l, elem j holds W[32kt + (l>>4)*8 + j][16ct + (l&15)].
// ---------------------------------------------------------------------------
__device__ __forceinline__ void packW(const float* __restrict__ W,
                                      short* __restrict__ out, int ncols, int ct,
                                      float scale)
{
    int t = threadIdx.x;
    int lane = t & 63, kt = (t >> 6) & 3;
    int g = lane >> 4, c = lane & 15;
    bf16x8 v;
    #pragma unroll
    for (int j = 0; j < 8; ++j)
        v[j] = f2bf(W[(kt * 32 + g * 8 + j) * ncols + ct * 16 + c] * scale);
    *(bf16x8*)(out + (size_t)(ct * 256 + t) * 8) = v;
}

__global__ __launch_bounds__(256)
void k_packall(const float* __restrict__ We2, const float* __restrict__ Wx1,
               const float* __restrict__ Wx2, const float* __restrict__ Wtp,
               const float* __restrict__ We1, const float* __restrict__ feat,
               short* __restrict__ We2p, short* __restrict__ Wx1p,
               short* __restrict__ Wx2p, short* __restrict__ Wtpp,
               short* __restrict__ We1Lp,
               float* __restrict__ FsP, float* __restrict__ FrP)
{
    const int b = blockIdx.x, t = threadIdx.x;
    if (b < 8)  { packW(We2, We2p, 128, b,      C2);       return; }
    if (b < 16) { packW(Wx1, Wx1p, 128, b - 8,  C2);       return; }
    if (b < 24) { packW(Wx2, Wx2p, 128, b - 16, C2);       return; }
    if (b < 28) { packW(Wtp, Wtpp,  64, b - 24, 0.03125f); return; } // 1/sqrt(U*V)
    if (b == 28) {
        // B-frags of We1 rows 0..7, K padded to 32, pre-scaled C1.
        #pragma unroll
        for (int h = 0; h < 2; ++h) {
            int tt = t + h * 256;
            int ct = tt >> 6, l = tt & 63, g = l >> 4, c = l & 15;
            bf16x8 v = {0,0,0,0,0,0,0,0};
            if (g == 0) {
                #pragma unroll
                for (int j = 0; j < 8; ++j)
                    v[j] = f2bf(We1[j * 128 + ct * 16 + c] * C1);
            }
            *(bf16x8*)(We1Lp + (size_t)tt * 8) = v;
        }
        return;
    }
    // ---- proj: 2 nodes per block, outputs pre-scaled by C1 ----
    __shared__ float sF[256];
    const int n = (b - 29) * 2 + (t >> 7), j = t & 127, hb = t & 128;
    sF[t] = feat[n * 128 + j];
    __syncthreads();
    float a = 0.f, bb = 0.f;
    #pragma unroll 8
    for (int k = 0; k < 128; ++k) {
        float f = sF[hb + k];
        a  = fmaf(f, We1[(8   + k) * 128 + j], a);
        bb = fmaf(f, We1[(136 + k) * 128 + j], bb);
    }
    FsP[n * 128 + j] = a * C1;
    FrP[n * 128 + j] = bb * C1;
}

// ---------------------------------------------------------------------------
// 16-col B-fragment loader (laundered against LICM)
// ---------------------------------------------------------------------------
__device__ __forceinline__ void loadB16(const short* __restrict__ p,
                                        bf16x8 (&B)[4], int w, int lane)
{
    int zz = 0; asm volatile("" : "+v"(zz));
    const bf16x8* p8 = (const bf16x8*)p;
    #pragma unroll
    for (int kt = 0; kt < 4; ++kt)
        B[kt] = p8[(w * 4 + kt) * 64 + lane + zz];
}

// 32-row x 16-col (per wave) GEMM over K=128 from swizzled LDS
__device__ __forceinline__ void gemm16(const short* sIn_, const bf16x8 (&B)[4],
                                       const int (&adrK)[4], f32x4 (&acc)[2])
{
    const char* sIn = (const char*)sIn_;
    const f32x4 z = {0.f, 0.f, 0.f, 0.f};
    acc[0] = z; acc[1] = z;
    __builtin_amdgcn_s_setprio(1);
    #pragma unroll
    for (int kt = 0; kt < 4; ++kt) {
        bf16x8 a0 = *(const bf16x8*)(sIn + adrK[kt]);
        bf16x8 a1 = *(const bf16x8*)(sIn + adrK[kt] + 4096);
        acc[0] = MFMA16(a0, B[kt], acc[0], 0, 0, 0);
        acc[1] = MFMA16(a1, B[kt], acc[1], 0, 0, 0);
    }
    __builtin_amdgcn_s_setprio(0);
}

// epilogue: pure silu -> bf16 (cvt_pk) scatter into LDS (optionally keep fp32)
template<bool KEEP>
__device__ __forceinline__ void epi16(const f32x4 (&acc)[2], short* sOut_,
                                      const int (&wAdr4)[4], f32x4 (&keep)[2])
{
    char* sOut = (char*)sOut_;
    #pragma unroll
    for (int rt = 0; rt < 2; ++rt) {
        float v0 = silu_f(acc[rt][0]);
        float v1 = silu_f(acc[rt][1]);
        float v2 = silu_f(acc[rt][2]);
        float v3 = silu_f(acc[rt][3]);
        if (KEEP) {
            keep[rt][0] = v0; keep[rt][1] = v1;
            keep[rt][2] = v2; keep[rt][3] = v3;
        }
        unsigned p01, p23;
        CVT_PK(p01, v0, v1);
        CVT_PK(p23, v2, v3);
        char* o = sOut + rt * 4096;
        *(short*)(o + wAdr4[0]) = (short)(p01 & 0xFFFFu);
        *(short*)(o + wAdr4[1]) = (short)(p01 >> 16);
        *(short*)(o + wAdr4[2]) = (short)(p23 & 0xFFFFu);
        *(short*)(o + wAdr4[3]) = (short)(p23 >> 16);
    }
}

// ---------------------------------------------------------------------------
// k_edge: one block per (sender, half); 8 chunks of 32 receivers.
// 512 threads = 8 waves x 16 cols -> ~70 regs/wave -> 6 waves/EU.
// ---------------------------------------------------------------------------
__global__ __launch_bounds__(512, 6)
void k_edge(const float* __restrict__ pos,
            const float* __restrict__ Winf,
            const float* __restrict__ FsP,
            const float* __restrict__ FrP,
            const short* __restrict__ We1Lp,
            const short* __restrict__ We2p,
            const short* __restrict__ Wx1p,
            const short* __restrict__ Wx2p,
            const short* __restrict__ Wtpp,
            float* __restrict__ MI2,
            float* __restrict__ VEC2)
{
    __shared__ __align__(16) short sX[CH * 128];     // activations ping (swizzled)
    __shared__ __align__(16) short sY[CH * 128];     // activations pong
    __shared__ __align__(16) float sLS[CH * NV * 4]; // (sh.xyz, len), v-slot swizzled
    __shared__ float sWinf[8 * 17];
    __shared__ float sPosS[24];
    __shared__ float sE[CH];
    __shared__ float sVp[4 * 24];

    const int bid = blockIdx.x;
    const int s = bid >> 1, half = bid & 1;
    const int t = threadIdx.x;
    const int lane = t & 63, w = t >> 6;          // 8 waves, 16 cols each
    const int rl = lane & 15, kg = lane >> 4;

    // ---- per-thread constant LDS byte addresses ----
    const int swz = (rl & 7) << 4;
    const int ktperm = (rl & 4) << 4;
    const int baseRd = rl * 256 + ((kg * 16) ^ (swz & 0x30));
    int adrK[4];
    #pragma unroll
    for (int kt = 0; kt < 4; ++kt) adrK[kt] = baseRd + ((kt * 64) ^ ktperm);
    int wAdr4[4];
    #pragma unroll
    for (int jj = 0; jj < 4; ++jj) {
        int r = kg * 4 + jj;
        wAdr4[jj] = r * 256 + ((w * 32 + 2 * rl) ^ ((r & 7) << 4));
    }
    const int colg = w * 16 + rl;
    // e-phase: 16 threads per row, 8 cols each
    const int erow = t >> 4, eseg = t & 15;
    const int eAdr = erow * 256 + ((eseg * 16) ^ ((erow & 7) << 4));
    const int vv = w * 2 + (rl >> 3);             // TP (waves 0-3): v index

    if (t < 128) sWinf[(t >> 4) * 17 + (t & 15)] = Winf[t];
    if (t < 24)  sPosS[t] = pos[s * 24 + t];

    const float fs0 = FsP[s * 128 + colg];        // pre-scaled C1

    float miacc0 = 0.f;
    float vax = 0.f, vay = 0.f, vaz = 0.f;
    __syncthreads();                                              // B0

    for (int c = 0; c < NCHH; ++c) {
        const int r0 = (half * NCHH + c) * CH;

        // ---- FrP loads (D-layout, 8 scalars) ----
        float frv[2][4];
        {
            int zz = 0; asm volatile("" : "+v"(zz));
            #pragma unroll
            for (int rt = 0; rt < 2; ++rt)
                #pragma unroll
                for (int jj = 0; jj < 4; ++jj)
                    frv[rt][jj] = FrP[(size_t)(r0 + rt * 16 + kg * 4 + jj) * 128 + colg + zz]
                                + fs0;
        }

        // ---- ph0: lengths + sh1 -> sLS (threads 0-255, 1 (r,v) pair each) ----
        if (t < 256) {
            int r = t >> 3, v = t & 7;
            const float* pr = pos + (size_t)(r0 + r) * 24 + v * 3;
            float dx = sPosS[v * 3 + 0] - pr[0];
            float dy = sPosS[v * 3 + 1] - pr[1];
            float dz = sPosS[v * 3 + 2] - pr[2];
            float sq = fmaxf(dx * dx + dy * dy + dz * dz, 1e-20f);
            float rs = __builtin_amdgcn_rsqf(sq);
            float len = sq * rs;                      // r==s -> sh1=0
            float inv = SQRT3 * rs;
            f32x4 o; o[0] = dx * inv; o[1] = dy * inv; o[2] = dz * inv; o[3] = len;
            *(f32x4*)(sLS + (r * 8 + (v ^ (r & 7))) * 4) = o;
        }
        __syncthreads();                                          // B1

        // ---- L1: lens @ We1L' with C = fr'+fs'; silu -> sX ----
        {
            bf16x8 bL0;
            {
                int zz = 0; asm volatile("" : "+v"(zz));
                bL0 = ((const bf16x8*)We1Lp)[w * 64 + lane + zz];
            }
            bf16x8 aL0 = {0,0,0,0,0,0,0,0}, aL1 = {0,0,0,0,0,0,0,0};
            if (kg == 0) {
                const float* Lp = sLS + rl * 32;
                const float* Lq = sLS + (rl + 16) * 32;
                unsigned u0[4], u1[4];
                #pragma unroll
                for (int jp = 0; jp < 4; ++jp) {
                    CVT_PK(u0[jp], Lp[((2*jp)   ^ (rl & 7)) * 4 + 3],
                                   Lp[((2*jp+1) ^ (rl & 7)) * 4 + 3]);
                    CVT_PK(u1[jp], Lq[((2*jp)   ^ (rl & 7)) * 4 + 3],
                                   Lq[((2*jp+1) ^ (rl & 7)) * 4 + 3]);
                }
                uint4 v0 = {u0[0], u0[1], u0[2], u0[3]};
                uint4 v1 = {u1[0], u1[1], u1[2], u1[3]};
                aL0 = __builtin_bit_cast(bf16x8, v0);
                aL1 = __builtin_bit_cast(bf16x8, v1);
            }
            f32x4 aP[2];
            aP[0] = MFMA16(aL0, bL0, *(const f32x4*)frv[0], 0, 0, 0);
            aP[1] = MFMA16(aL1, bL0, *(const f32x4*)frv[1], 0, 0, 0);
            f32x4 dummy[2];
            epi16<false>(aP, sX, wAdr4, dummy);
        }
        __syncthreads();                                          // B2

        // ---- L2: m_ij = silu(a1 @ We2') -> sY ; keep fp32 ----
        f32x4 acc[2], keepM[2];
        {
            bf16x8 B[4];
            loadB16(We2p, B, w, lane);
            gemm16(sX, B, adrK, acc);
            epi16<true>(acc, sY, wAdr4, keepM);
        }
        __syncthreads();                                          // B3

        // ---- e[r] = sigmoid(C2 * m_ij . Winf)  (16 threads/row, 8 cols each) ----
        {
            uint4 m = *(const uint4*)((const char*)sY + eAdr);
            const unsigned mu[4] = {m.x, m.y, m.z, m.w};
            const float* wf = sWinf + (eseg >> 1) * 17 + (eseg & 1) * 8;
            float d = 0.f;
            #pragma unroll
            for (int i = 0; i < 4; ++i) {
                d = fmaf(bflo(mu[i]), wf[2 * i],     d);
                d = fmaf(bfhi(mu[i]), wf[2 * i + 1], d);
            }
            d += __shfl_xor(d, 1); d += __shfl_xor(d, 2);
            d += __shfl_xor(d, 4); d += __shfl_xor(d, 8);
            if (eseg == 0) sE[erow] = (r0 + erow == s) ? 0.f : sigm_f(d * C2);
        }
        __syncthreads();                                          // B4

        // ---- m_i accumulation from registers ----
        #pragma unroll
        for (int rt = 0; rt < 2; ++rt)
            #pragma unroll
            for (int jj = 0; jj < 4; ++jj)
                miacc0 = fmaf(keepM[rt][jj], sE[rt * 16 + kg * 4 + jj], miacc0);

        // ---- L3: phi_x layer 1 ----
        {
            bf16x8 B[4];
            loadB16(Wx1p, B, w, lane);
            gemm16(sY, B, adrK, acc);
            epi16<false>(acc, sX, wAdr4, keepM);
        }
        __syncthreads();                                          // B5

        // ---- L4: phi_x layer 2 ----
        {
            bf16x8 B[4];
            loadB16(Wx2p, B, w, lane);
            gemm16(sX, B, adrK, acc);
            epi16<false>(acc, sY, wAdr4, keepM);
        }
        __syncthreads();                                          // B6

        // ---- TP gemm (waves 0-3, 16 cols each; Wtp' includes 1/32) ----
        if (w < 4) {
            bf16x8 Bt[4];
            loadB16(Wtpp, Bt, w, lane);
            f32x4 a2[2];
            gemm16(sY, Bt, adrK, a2);
            #pragma unroll
            for (int rt = 0; rt < 2; ++rt)
                #pragma unroll
                for (int jj = 0; jj < 4; ++jj) {
                    int row = rt * 16 + kg * 4 + jj;
                    const f32x4 sh = *(const f32x4*)(sLS + (row * 8 + (vv ^ (row & 7))) * 4);
                    float g = a2[rt][jj];
                    vax = fmaf(g, sh[0], vax);
                    vay = fmaf(g, sh[1], vay);
                    vaz = fmaf(g, sh[2], vaz);
                }
        }
        __syncthreads();                                          // B7
    }

    // ---- epilogue: m_i reduce over kg row-groups ----
    miacc0 += __shfl_xor(miacc0, 16); miacc0 += __shfl_xor(miacc0, 32);
    if (lane < 16) {
        MI2[(size_t)(half * NN + s) * 128 + w * 16 + lane] = miacc0;
    }
    // ---- vec reduce (waves 0-3; 1/32 folded into Wtpp) ----
    if (w < 4) {
        vax += __shfl_xor(vax, 8);  vay += __shfl_xor(vay, 8);  vaz += __shfl_xor(vaz, 8);
        vax += __shfl_xor(vax, 16); vay += __shfl_xor(vay, 16); vaz += __shfl_xor(vaz, 16);
        vax += __shfl_xor(vax, 32); vay += __shfl_xor(vay, 32); vaz += __shfl_xor(vaz, 32);
        if ((lane & 56) == 0) {
            float* vp = sVp + w * 24 + lane * 3;
            vp[0] = vax; vp[1] = vay; vp[2] = vaz;
        }
    }
    __syncthreads();
    if (t < 24) {
        float sum = sVp[t] + sVp[24 + t] + sVp[48 + t] + sVp[72 + t];
        VEC2[(size_t)(half * NN + s) * 24 + t] = sum;
    }
}

// ---------------------------------------------------------------------------
// k_node: per-node h-MLP + residual + position update (sums the 2 halves).
// ---------------------------------------------------------------------------
__global__ __launch_bounds__(128)
void k_node(const float* __restrict__ pos, const float* __restrict__ feat,
            const float* __restrict__ Wh1, const float* __restrict__ Wh2,
            const float* __restrict__ Wh3,
            const float* __restrict__ MI2, const float* __restrict__ VEC2,
            float* __restrict__ outPos, float* __restrict__ outFeat)
{
    __shared__ float sMi[128], sF[128], sH[128];
    int n = blockIdx.x, j = threadIdx.x;
    sMi[j] = MI2[n * 128 + j] + MI2[NN * 128 + n * 128 + j];
    sF[j]  = feat[n * 128 + j];
    __syncthreads();
    float a = 0.f;
    #pragma unroll 8
    for (int k = 0; k < 128; ++k) a = fmaf(sMi[k], Wh1[k * 128 + j], a);
    #pragma unroll 8
    for (int k = 0; k < 128; ++k) a = fmaf(sF[k], Wh1[(128 + k) * 128 + j], a);
    a = silu_f(a * 0.0625f);            // 1/sqrt(256)
    sH[j] = a;
    __syncthreads();
    float b = 0.f;
    #pragma unroll 8
    for (int k = 0; k < 128; ++k) b = fmaf(sH[k], Wh2[k * 128 + j], b);
    b = silu_f(b * C2);
    sMi[j] = b;
    __syncthreads();
    float cc = 0.f;
    #pragma unroll 8
    for (int k = 0; k < 128; ++k) cc = fmaf(sMi[k], Wh3[k * 128 + j], cc);
    outFeat[n * 128 + j] = cc * C2 + sF[j];
    if (j < 24) outPos[n * 24 + j] = pos[n * 24 + j]
                                   + VEC2[n * 24 + j] + VEC2[NN * 24 + n * 24 + j];
}

// ---------------------------------------------------------------------------
extern "C" void kernel_launch(void* const* d_in, const int* in_sizes, int n_in,
                              void* d_out, int out_size, void* d_ws, size_t ws_size,
                              hipStream_t stream) {
    const float* pos  = (const float*)d_in[0];
    const float* feat = (const float*)d_in[1];
    const float* We1  = (const float*)d_in[2];
    const float* We2  = (const float*)d_in[3];
    const float* Wx1  = (const float*)d_in[4];
    const float* Wx2  = (const float*)d_in[5];
    const float* Winf = (const float*)d_in[6];
    const float* Wtp  = (const float*)d_in[7];
    const float* Wh1  = (const float*)d_in[8];
    const float* Wh2  = (const float*)d_in[9];
    const float* Wh3  = (const float*)d_in[10];

    float* outPos  = (float*)d_out;              // [512*8*3]
    float* outFeat = (float*)d_out + NN * 24;    // [512*128]

    float* ws   = (float*)d_ws;
    float* FsP  = ws;                   // 65536 floats (pre-scaled C1)
    float* FrP  = ws + 65536;           // 65536 (pre-scaled C1)
    float* MI2  = ws + 131072;          // 2*65536
    float* VEC2 = ws + 262144;          // 2*12288
    short* wpack = (short*)(ws + 286720);
    short* We2p  = wpack;               // 16384 shorts (pre-scaled C2)
    short* Wx1p  = wpack + 16384;       // 16384 (C2)
    short* Wx2p  = wpack + 32768;       // 16384 (C2)
    short* Wtpp  = wpack + 49152;       // 8192  (1/32)
    short* We1Lp = wpack + 57344;       // 4096  (C1)

    k_packall<<<dim3(285), dim3(256), 0, stream>>>(We2, Wx1, Wx2, Wtp, We1, feat,
                                                   We2p, Wx1p, Wx2p, Wtpp, We1Lp,
                                                   FsP, FrP);
    k_edge<<<dim3(2 * NN), dim3(512), 0, stream>>>(pos, Winf, FsP, FrP, We1Lp,
                                                   We2p, Wx1p, Wx2p, Wtpp, MI2, VEC2);
    k_node<<<dim3(NN), dim3(128), 0, stream>>>(pos, feat, Wh1, Wh2, Wh3, MI2, VEC2,
                                               outPos, outFeat);
}

// Round 14
// 92.788 us; speedup vs baseline: 1.4895x; 1.3813x over previous
//
#include <hip/hip_runtime.h>
#include <math.h>

#define NN   512
#define NV   8
#define CH   32      // receivers per chunk
#define NCHH 8       // chunks per half-block (2 blocks per sender)
#define SPB  272     // activation LDS row stride in BYTES (17*16: bank-phase pad)

#define C1 0.06154574548966636f   // 1/sqrt(264)
#define C2 0.08838834764831845f   // 1/sqrt(128)
#define SQRT3 1.7320508075688772f

typedef __attribute__((ext_vector_type(8))) short bf16x8;   // 8 bf16 = 4 VGPRs
typedef __attribute__((ext_vector_type(4))) float f32x4;

#define MFMA16 __builtin_amdgcn_mfma_f32_16x16x32_bf16
#define CVT_PK(dst, a, b) asm("v_cvt_pk_bf16_f32 %0, %1, %2" : "=v"(dst) : "v"(a), "v"(b))

__device__ __forceinline__ float silu_f(float x) {
    float e = __builtin_amdgcn_exp2f(x * -1.442695041f);
    return x * __builtin_amdgcn_rcpf(1.0f + e);
}
__device__ __forceinline__ float sigm_f(float x) {
    float e = __builtin_amdgcn_exp2f(x * -1.442695041f);
    return __builtin_amdgcn_rcpf(1.0f + e);
}
__device__ __forceinline__ short f2bf(float f) {
    unsigned u = __builtin_bit_cast(unsigned, f);
    u = (u + 0x7FFFu + ((u >> 16) & 1u)) >> 16;
    return (short)u;
}
__device__ __forceinline__ float bfhi(unsigned u) {
    return __builtin_bit_cast(float, u & 0xFFFF0000u);
}
__device__ __forceinline__ float bflo(unsigned u) {
    return __builtin_bit_cast(float, u << 16);
}

// ---------------------------------------------------------------------------
// k_packall: all weight packing + proj in ONE launch; weights PRE-SCALED.
// Frag (ct,kt), lane l, elem j holds W[32kt + (l>>4)*8 + j][16ct + (l&15)].
// ---------------------------------------------------------------------------
__device__ __forceinline__ void packW(const float* __restrict__ W,
                                      short* __restrict__ out, int ncols, int ct,
                                      float scale)
{
    int t = threadIdx.x;
    int lane = t & 63, kt = (t >> 6) & 3;
    int g = lane >> 4, c = lane & 15;
    bf16x8 v;
    #pragma unroll
    for (int j = 0; j < 8; ++j)
        v[j] = f2bf(W[(kt * 32 + g * 8 + j) * ncols + ct * 16 + c] * scale);
    *(bf16x8*)(out + (size_t)(ct * 256 + t) * 8) = v;
}

__global__ __launch_bounds__(256)
void k_packall(const float* __restrict__ We2, const float* __restrict__ Wx1,
               const float* __restrict__ Wx2, const float* __restrict__ Wtp,
               const float* __restrict__ We1, const float* __restrict__ feat,
               short* __restrict__ We2p, short* __restrict__ Wx1p,
               short* __restrict__ Wx2p, short* __restrict__ Wtpp,
               short* __restrict__ We1Lp,
               float* __restrict__ FsP, float* __restrict__ FrP)
{
    const int b = blockIdx.x, t = threadIdx.x;
    if (b < 8)  { packW(We2, We2p, 128, b,      C2);       return; }
    if (b < 16) { packW(Wx1, Wx1p, 128, b - 8,  C2);       return; }
    if (b < 24) { packW(Wx2, Wx2p, 128, b - 16, C2);       return; }
    if (b < 28) { packW(Wtp, Wtpp,  64, b - 24, 0.03125f); return; } // 1/sqrt(U*V)
    if (b == 28) {
        // B-frags of We1 rows 0..7, K padded to 32, pre-scaled C1.
        #pragma unroll
        for (int h = 0; h < 2; ++h) {
            int tt = t + h * 256;
            int ct = tt >> 6, l = tt & 63, g = l >> 4, c = l & 15;
            bf16x8 v = {0,0,0,0,0,0,0,0};
            if (g == 0) {
                #pragma unroll
                for (int j = 0; j < 8; ++j)
                    v[j] = f2bf(We1[j * 128 + ct * 16 + c] * C1);
            }
            *(bf16x8*)(We1Lp + (size_t)tt * 8) = v;
        }
        return;
    }
    // ---- proj: 2 nodes per block, outputs pre-scaled by C1 ----
    __shared__ float sF[256];
    const int n = (b - 29) * 2 + (t >> 7), j = t & 127, hb = t & 128;
    sF[t] = feat[n * 128 + j];
    __syncthreads();
    float a = 0.f, bb = 0.f;
    #pragma unroll 8
    for (int k = 0; k < 128; ++k) {
        float f = sF[hb + k];
        a  = fmaf(f, We1[(8   + k) * 128 + j], a);
        bb = fmaf(f, We1[(136 + k) * 128 + j], bb);
    }
    FsP[n * 128 + j] = a * C1;
    FrP[n * 128 + j] = bb * C1;
}

// ---------------------------------------------------------------------------
// laundered B-fragment loader (anchors loads at the call site, defeats LICM)
// ---------------------------------------------------------------------------
__device__ __forceinline__ void loadBz(const short* __restrict__ p,
                                       bf16x8 (&B)[2][4], int w, int lane)
{
    int zz = 0; asm volatile("" : "+v"(zz));
    const bf16x8* p8 = (const bf16x8*)p;
    #pragma unroll
    for (int ctl = 0; ctl < 2; ++ctl)
        #pragma unroll
        for (int kt = 0; kt < 4; ++kt)
            B[ctl][kt] = p8[((w * 2 + ctl) * 4 + kt) * 64 + lane + zz];
}

// MFMA-only part of the 32x128 @ 128x128 layer (weights pre-scaled).
// A reads at stride-SPB rows: bank phase advances 16B/row -> conflict-free.
__device__ __forceinline__ void gemm_mfma(const short* sIn_, const bf16x8 (&B)[2][4],
                                          const int (&adrK)[4], f32x4 (&acc)[2][2])
{
    const char* sIn = (const char*)sIn_;
    const f32x4 z = {0.f, 0.f, 0.f, 0.f};
    acc[0][0] = z; acc[0][1] = z; acc[1][0] = z; acc[1][1] = z;
    __builtin_amdgcn_s_setprio(1);
    #pragma unroll
    for (int kt = 0; kt < 4; ++kt) {
        bf16x8 a0 = *(const bf16x8*)(sIn + adrK[kt]);
        bf16x8 a1 = *(const bf16x8*)(sIn + adrK[kt] + 16 * SPB);
        acc[0][0] = MFMA16(a0, B[0][kt], acc[0][0], 0, 0, 0);
        acc[0][1] = MFMA16(a0, B[1][kt], acc[0][1], 0, 0, 0);
        acc[1][0] = MFMA16(a1, B[0][kt], acc[1][0], 0, 0, 0);
        acc[1][1] = MFMA16(a1, B[1][kt], acc[1][1], 0, 0, 0);
    }
    __builtin_amdgcn_s_setprio(0);
}

// epilogue: pure silu -> bf16 (cvt_pk) scatter into LDS (optionally keep fp32)
template<bool KEEP>
__device__ __forceinline__ void epi_store(const f32x4 (&acc)[2][2], short* sOut_,
                                          const int (&wAdr)[2][4], f32x4 (&keep)[2][2])
{
    char* sOut = (char*)sOut_;
    #pragma unroll
    for (int rt = 0; rt < 2; ++rt)
        #pragma unroll
        for (int ctl = 0; ctl < 2; ++ctl) {
            float v0 = silu_f(acc[rt][ctl][0]);
            float v1 = silu_f(acc[rt][ctl][1]);
            float v2 = silu_f(acc[rt][ctl][2]);
            float v3 = silu_f(acc[rt][ctl][3]);
            if (KEEP) {
                keep[rt][ctl][0] = v0; keep[rt][ctl][1] = v1;
                keep[rt][ctl][2] = v2; keep[rt][ctl][3] = v3;
            }
            unsigned p01, p23;
            CVT_PK(p01, v0, v1);
            CVT_PK(p23, v2, v3);
            char* o = sOut + rt * 16 * SPB;
            *(short*)(o + wAdr[ctl][0]) = (short)(p01 & 0xFFFFu);
            *(short*)(o + wAdr[ctl][1]) = (short)(p01 >> 16);
            *(short*)(o + wAdr[ctl][2]) = (short)(p23 & 0xFFFFu);
            *(short*)(o + wAdr[ctl][3]) = (short)(p23 >> 16);
        }
}

// ---------------------------------------------------------------------------
// k_edge: one block per (sender, half); 8 chunks of 32 receivers.
// R9 structure; activation LDS rows padded to 272B (no XOR swizzle needed).
// ---------------------------------------------------------------------------
__global__ __launch_bounds__(256, 4)
void k_edge(const float* __restrict__ pos,
            const float* __restrict__ Winf,
            const float* __restrict__ FsP,
            const float* __restrict__ FrP,
            const short* __restrict__ We1Lp,
            const short* __restrict__ We2p,
            const short* __restrict__ Wx1p,
            const short* __restrict__ Wx2p,
            const short* __restrict__ Wtpp,
            float* __restrict__ MI2,
            float* __restrict__ VEC2)
{
    __shared__ __align__(16) short sX[CH * (SPB / 2)];   // ping, padded rows
    __shared__ __align__(16) short sY[CH * (SPB / 2)];   // pong
    __shared__ __align__(16) float sLS[CH * NV * 4];     // (sh.xyz,len), v-swizzled
    __shared__ float sWinf[8 * 17];
    __shared__ float sPosS[24];
    __shared__ float sE[CH];
    __shared__ float sVp[4 * 24];

    const int bid = blockIdx.x;
    const int s = bid >> 1, half = bid & 1;
    const int t = threadIdx.x;
    const int lane = t & 63, w = t >> 6;
    const int rl = lane & 15, kg = lane >> 4;

    // ---- per-thread constant LDS byte addresses (linear, padded stride) ----
    int adrK[4];
    #pragma unroll
    for (int kt = 0; kt < 4; ++kt) adrK[kt] = rl * SPB + kg * 16 + kt * 64;
    int wAdr[2][4];
    #pragma unroll
    for (int ctl = 0; ctl < 2; ++ctl)
        #pragma unroll
        for (int jj = 0; jj < 4; ++jj) {
            int r = kg * 4 + jj;
            wAdr[ctl][jj] = r * SPB + w * 64 + ctl * 32 + 2 * rl;
        }
    const int colg0 = w * 32 + rl, colg1 = colg0 + 16;
    const int er = t >> 3, eo = t & 7;
    const int eAdr0 = er * SPB + eo * 32;
    const int eAdr1 = eAdr0 + 16;
    const int vv = w * 2 + (rl >> 3);

    if (t < 128) sWinf[(t >> 4) * 17 + (t & 15)] = Winf[t];
    if (t < 24)  sPosS[t] = pos[s * 24 + t];

    const float fs0 = FsP[s * 128 + colg0];   // pre-scaled C1
    const float fs1 = FsP[s * 128 + colg1];

    float miacc0 = 0.f, miacc1 = 0.f;
    float vax = 0.f, vay = 0.f, vaz = 0.f;
    __syncthreads();                                              // B0

    for (int c = 0; c < NCHH; ++c) {
        const int r0 = (half * NCHH + c) * CH;

        // ==== chunk-top issue: We2 frags + We1L frags + FrP->C-operand ====
        bf16x8 Bw[2][4];
        loadBz(We2p, Bw, w, lane);
        bf16x8 bL0, bL1;
        {
            int zz = 0; asm volatile("" : "+v"(zz));
            const bf16x8* pL = (const bf16x8*)We1Lp;
            bL0 = pL[(w * 2 + 0) * 64 + lane + zz];
            bL1 = pL[(w * 2 + 1) * 64 + lane + zz];
        }
        f32x4 cIn[2][2];
        {
            int zz = 0; asm volatile("" : "+v"(zz));
            #pragma unroll
            for (int rt = 0; rt < 2; ++rt)
                #pragma unroll
                for (int jj = 0; jj < 4; ++jj) {
                    const float* fp = FrP + (size_t)(r0 + rt * 16 + kg * 4 + jj) * 128 + zz;
                    cIn[rt][0][jj] = fp[colg0] + fs0;   // acc-init = fr' + fs'
                    cIn[rt][1][jj] = fp[colg1] + fs1;
                }
        }

        // ---- ph0: lengths + sh1 -> sLS (block-shared, 1 (r,v) pair/thread) ----
        {
            int r = t >> 3, v = t & 7;
            const float* pr = pos + (size_t)(r0 + r) * 24 + v * 3;
            float dx = sPosS[v * 3 + 0] - pr[0];
            float dy = sPosS[v * 3 + 1] - pr[1];
            float dz = sPosS[v * 3 + 2] - pr[2];
            float sq = fmaxf(dx * dx + dy * dy + dz * dz, 1e-20f);
            float rs = __builtin_amdgcn_rsqf(sq);
            float len = sq * rs;                      // = sqrt(sq); r==s -> sh1=0
            float inv = SQRT3 * rs;
            f32x4 o; o[0] = dx * inv; o[1] = dy * inv; o[2] = dz * inv; o[3] = len;
            *(f32x4*)(sLS + (r * 8 + (v ^ (r & 7))) * 4) = o;
        }
        __syncthreads();                                          // B1

        // ---- L1: lens @ We1L' with C-operand = fr'+fs'; pure-silu epi -> sX ----
        {
            bf16x8 aL0 = {0,0,0,0,0,0,0,0}, aL1 = {0,0,0,0,0,0,0,0};
            if (kg == 0) {
                const float* Lp = sLS + rl * 32;
                const float* Lq = sLS + (rl + 16) * 32;
                unsigned u0[4], u1[4];
                #pragma unroll
                for (int jp = 0; jp < 4; ++jp) {
                    CVT_PK(u0[jp], Lp[((2*jp)   ^ (rl & 7)) * 4 + 3],
                                   Lp[((2*jp+1) ^ (rl & 7)) * 4 + 3]);
                    CVT_PK(u1[jp], Lq[((2*jp)   ^ (rl & 7)) * 4 + 3],
                                   Lq[((2*jp+1) ^ (rl & 7)) * 4 + 3]);
                }
                uint4 v0 = {u0[0], u0[1], u0[2], u0[3]};
                uint4 v1 = {u1[0], u1[1], u1[2], u1[3]};
                aL0 = __builtin_bit_cast(bf16x8, v0);
                aL1 = __builtin_bit_cast(bf16x8, v1);
            }
            f32x4 aP[2][2];
            aP[0][0] = MFMA16(aL0, bL0, cIn[0][0], 0, 0, 0);
            aP[0][1] = MFMA16(aL0, bL1, cIn[0][1], 0, 0, 0);
            aP[1][0] = MFMA16(aL1, bL0, cIn[1][0], 0, 0, 0);
            aP[1][1] = MFMA16(aL1, bL1, cIn[1][1], 0, 0, 0);
            f32x4 dummy[2][2];
            epi_store<false>(aP, sX, wAdr, dummy);
        }
        __syncthreads();                                          // B2

        // ---- L2: m_ij = silu(a1 @ We2') -> sY ; Wx1 issued under epilogue ----
        f32x4 acc[2][2];
        f32x4 keepM[2][2];
        gemm_mfma(sX, Bw, adrK, acc);          // consumes We2 (Bw regs die)
        bf16x8 Bn[2][4];
        loadBz(Wx1p, Bn, w, lane);             // Wx1 in flight: epi + e-phase
        epi_store<true>(acc, sY, wAdr, keepM);
        __syncthreads();                                          // B3

        // ---- e[r] = sigmoid(C2 * m_ij . Winf) ----
        {
            const char* sYc = (const char*)sY;
            uint4 m0 = *(const uint4*)(sYc + eAdr0);
            uint4 m1 = *(const uint4*)(sYc + eAdr1);
            const unsigned mu[8] = {m0.x, m0.y, m0.z, m0.w, m1.x, m1.y, m1.z, m1.w};
            float d = 0.f;
            #pragma unroll
            for (int q = 0; q < 8; ++q) {
                d = fmaf(bflo(mu[q]), sWinf[eo * 17 + 2 * q],     d);
                d = fmaf(bfhi(mu[q]), sWinf[eo * 17 + 2 * q + 1], d);
            }
            d += __shfl_xor(d, 1); d += __shfl_xor(d, 2); d += __shfl_xor(d, 4);
            if (eo == 0) sE[er] = (r0 + er == s) ? 0.f : sigm_f(d * C2);
        }
        __syncthreads();                                          // B4

        // ---- m_i accumulation from registers ----
        #pragma unroll
        for (int rt = 0; rt < 2; ++rt)
            #pragma unroll
            for (int jj = 0; jj < 4; ++jj) {
                float e = sE[rt * 16 + kg * 4 + jj];
                miacc0 = fmaf(keepM[rt][0][jj], e, miacc0);
                miacc1 = fmaf(keepM[rt][1][jj], e, miacc1);
            }

        // ---- L3: phi_x layer 1 ; Wx2 issued under epilogue ----
        gemm_mfma(sY, Bn, adrK, acc);          // consumes Wx1
        loadBz(Wx2p, Bw, w, lane);             // Wx2 in flight: epi + barrier
        epi_store<false>(acc, sX, wAdr, keepM);
        __syncthreads();                                          // B5

        // ---- L4: phi_x layer 2 ; Wtp issued under epilogue ----
        gemm_mfma(sX, Bw, adrK, acc);          // consumes Wx2
        bf16x8 Bt[4];
        {
            int zz = 0; asm volatile("" : "+v"(zz));
            const bf16x8* p8 = (const bf16x8*)Wtpp;
            #pragma unroll
            for (int kt = 0; kt < 4; ++kt) Bt[kt] = p8[(w * 4 + kt) * 64 + lane + zz];
        }
        epi_store<false>(acc, sY, wAdr, keepM);
        __syncthreads();                                          // B6

        // ---- TP gemm (Wtp' includes 1/32) + vec acc from regs ----
        {
            const f32x4 z = {0.f, 0.f, 0.f, 0.f};
            f32x4 acc0 = z, acc1 = z;
            const char* sYc = (const char*)sY;
            __builtin_amdgcn_s_setprio(1);
            #pragma unroll
            for (int kt = 0; kt < 4; ++kt) {
                bf16x8 a0 = *(const bf16x8*)(sYc + adrK[kt]);
                bf16x8 a1 = *(const bf16x8*)(sYc + adrK[kt] + 16 * SPB);
                acc0 = MFMA16(a0, Bt[kt], acc0, 0, 0, 0);
                acc1 = MFMA16(a1, Bt[kt], acc1, 0, 0, 0);
            }
            __builtin_amdgcn_s_setprio(0);
            #pragma unroll
            for (int rt = 0; rt < 2; ++rt)
                #pragma unroll
                for (int jj = 0; jj < 4; ++jj) {
                    int row = rt * 16 + kg * 4 + jj;
                    const f32x4 sh = *(const f32x4*)(sLS + (row * 8 + (vv ^ (row & 7))) * 4);
                    float g = rt ? acc1[jj] : acc0[jj];
                    vax = fmaf(g, sh[0], vax);
                    vay = fmaf(g, sh[1], vay);
                    vaz = fmaf(g, sh[2], vaz);
                }
        }
        __syncthreads();                                          // B7
    }

    // ---- epilogue: m_i reduce over row-groups ----
    miacc0 += __shfl_xor(miacc0, 16); miacc0 += __shfl_xor(miacc0, 32);
    miacc1 += __shfl_xor(miacc1, 16); miacc1 += __shfl_xor(miacc1, 32);
    if (lane < 16) {
        float* mo = MI2 + (size_t)(half * NN + s) * 128;
        mo[w * 32 + lane]      = miacc0;
        mo[w * 32 + 16 + lane] = miacc1;
    }
    // ---- vec reduce (1/32 folded into Wtpp) ----
    vax += __shfl_xor(vax, 8);  vay += __shfl_xor(vay, 8);  vaz += __shfl_xor(vaz, 8);
    vax += __shfl_xor(vax, 16); vay += __shfl_xor(vay, 16); vaz += __shfl_xor(vaz, 16);
    vax += __shfl_xor(vax, 32); vay += __shfl_xor(vay, 32); vaz += __shfl_xor(vaz, 32);
    if ((lane & 56) == 0) {
        float* vp = sVp + w * 24 + lane * 3;
        vp[0] = vax; vp[1] = vay; vp[2] = vaz;
    }
    __syncthreads();
    if (t < 24) {
        float sum = sVp[t] + sVp[24 + t] + sVp[48 + t] + sVp[72 + t];
        VEC2[(size_t)(half * NN + s) * 24 + t] = sum;
    }
}

// ---------------------------------------------------------------------------
// k_node: per-node h-MLP + residual + position update (sums the 2 halves).
// ---------------------------------------------------------------------------
__global__ __launch_bounds__(128)
void k_node(const float* __restrict__ pos, const float* __restrict__ feat,
            const float* __restrict__ Wh1, const float* __restrict__ Wh2,
            const float* __restrict__ Wh3,
            const float* __restrict__ MI2, const float* __restrict__ VEC2,
            float* __restrict__ outPos, float* __restrict__ outFeat)
{
    __shared__ float sMi[128], sF[128], sH[128];
    int n = blockIdx.x, j = threadIdx.x;
    sMi[j] = MI2[n * 128 + j] + MI2[NN * 128 + n * 128 + j];
    sF[j]  = feat[n * 128 + j];
    __syncthreads();
    float a = 0.f;
    #pragma unroll 8
    for (int k = 0; k < 128; ++k) a = fmaf(sMi[k], Wh1[k * 128 + j], a);
    #pragma unroll 8
    for (int k = 0; k < 128; ++k) a = fmaf(sF[k], Wh1[(128 + k) * 128 + j], a);
    a = silu_f(a * 0.0625f);            // 1/sqrt(256)
    sH[j] = a;
    __syncthreads();
    float b = 0.f;
    #pragma unroll 8
    for (int k = 0; k < 128; ++k) b = fmaf(sH[k], Wh2[k * 128 + j], b);
    b = silu_f(b * C2);
    sMi[j] = b;
    __syncthreads();
    float cc = 0.f;
    #pragma unroll 8
    for (int k = 0; k < 128; ++k) cc = fmaf(sMi[k], Wh3[k * 128 + j], cc);
    outFeat[n * 128 + j] = cc * C2 + sF[j];
    if (j < 24) outPos[n * 24 + j] = pos[n * 24 + j]
                                   + VEC2[n * 24 + j] + VEC2[NN * 24 + n * 24 + j];
}

// ---------------------------------------------------------------------------
extern "C" void kernel_launch(void* const* d_in, const int* in_sizes, int n_in,
                              void* d_out, int out_size, void* d_ws, size_t ws_size,
                              hipStream_t stream) {
    const float* pos  = (const float*)d_in[0];
    const float* feat = (const float*)d_in[1];
    const float* We1  = (const float*)d_in[2];
    const float* We2  = (const float*)d_in[3];
    const float* Wx1  = (const float*)d_in[4];
    const float* Wx2  = (const float*)d_in[5];
    const float* Winf = (const float*)d_in[6];
    const float* Wtp  = (const float*)d_in[7];
    const float* Wh1  = (const float*)d_in[8];
    const float* Wh2  = (const float*)d_in[9];
    const float* Wh3  = (const float*)d_in[10];

    float* outPos  = (float*)d_out;              // [512*8*3]
    float* outFeat = (float*)d_out + NN * 24;    // [512*128]

    float* ws   = (float*)d_ws;
    float* FsP  = ws;                   // 65536 floats (pre-scaled C1)
    float* FrP  = ws + 65536;           // 65536 (pre-scaled C1)
    float* MI2  = ws + 131072;          // 2*65536
    float* VEC2 = ws + 262144;          // 2*12288
    short* wpack = (short*)(ws + 286720);
    short* We2p  = wpack;               // 16384 shorts (pre-scaled C2)
    short* Wx1p  = wpack + 16384;       // 16384 (C2)
    short* Wx2p  = wpack + 32768;       // 16384 (C2)
    short* Wtpp  = wpack + 49152;       // 8192  (1/32)
    short* We1Lp = wpack + 57344;       // 4096  (C1)

    k_packall<<<dim3(285), dim3(256), 0, stream>>>(We2, Wx1, Wx2, Wtp, We1, feat,
                                                   We2p, Wx1p, Wx2p, Wtpp, We1Lp,
                                                   FsP, FrP);
    k_edge<<<dim3(2 * NN), dim3(256), 0, stream>>>(pos, Winf, FsP, FrP, We1Lp,
                                                   We2p, Wx1p, Wx2p, Wtpp, MI2, VEC2);
    k_node<<<dim3(NN), dim3(128), 0, stream>>>(pos, feat, Wh1, Wh2, Wh3, MI2, VEC2,
                                               outPos, outFeat);
}

// Round 15
// 90.930 us; speedup vs baseline: 1.5200x; 1.0204x over previous
//
#include <hip/hip_runtime.h>
#include <math.h>

#define NN   512
#define NV   8
#define CH   32      // receivers per chunk
#define NCHH 8       // chunks per half-block (2 blocks per sender)
#define SPB  272     // activation LDS row stride in BYTES (17*16: bank-phase pad)

#define C1 0.06154574548966636f   // 1/sqrt(264)
#define C2 0.08838834764831845f   // 1/sqrt(128)
#define SQRT3 1.7320508075688772f

typedef __attribute__((ext_vector_type(8))) short bf16x8;   // 8 bf16 = 4 VGPRs
typedef __attribute__((ext_vector_type(4))) float f32x4;

#define MFMA16 __builtin_amdgcn_mfma_f32_16x16x32_bf16
#define CVT_PK(dst, a, b) asm("v_cvt_pk_bf16_f32 %0, %1, %2" : "=v"(dst) : "v"(a), "v"(b))

__device__ __forceinline__ float silu_f(float x) {
    float e = __builtin_amdgcn_exp2f(x * -1.442695041f);
    return x * __builtin_amdgcn_rcpf(1.0f + e);
}
__device__ __forceinline__ float sigm_f(float x) {
    float e = __builtin_amdgcn_exp2f(x * -1.442695041f);
    return __builtin_amdgcn_rcpf(1.0f + e);
}
__device__ __forceinline__ short f2bf(float f) {
    unsigned u = __builtin_bit_cast(unsigned, f);
    u = (u + 0x7FFFu + ((u >> 16) & 1u)) >> 16;
    return (short)u;
}
__device__ __forceinline__ float bfhi(unsigned u) {
    return __builtin_bit_cast(float, u & 0xFFFF0000u);
}
__device__ __forceinline__ float bflo(unsigned u) {
    return __builtin_bit_cast(float, u << 16);
}

// ---------------------------------------------------------------------------
// k_packall: all weight packing + proj in ONE launch; weights PRE-SCALED.
// Frag (ct,kt), lane l, elem j holds W[32kt + (l>>4)*8 + j][16ct + (l&15)].
// ---------------------------------------------------------------------------
__device__ __forceinline__ void packW(const float* __restrict__ W,
                                      short* __restrict__ out, int ncols, int ct,
                                      float scale)
{
    int t = threadIdx.x;
    int lane = t & 63, kt = (t >> 6) & 3;
    int g = lane >> 4, c = lane & 15;
    bf16x8 v;
    #pragma unroll
    for (int j = 0; j < 8; ++j)
        v[j] = f2bf(W[(kt * 32 + g * 8 + j) * ncols + ct * 16 + c] * scale);
    *(bf16x8*)(out + (size_t)(ct * 256 + t) * 8) = v;
}

__global__ __launch_bounds__(256)
void k_packall(const float* __restrict__ We2, const float* __restrict__ Wx1,
               const float* __restrict__ Wx2, const float* __restrict__ Wtp,
               const float* __restrict__ We1, const float* __restrict__ feat,
               short* __restrict__ We2p, short* __restrict__ Wx1p,
               short* __restrict__ Wx2p, short* __restrict__ Wtpp,
               short* __restrict__ We1Lp,
               float* __restrict__ FsP, float* __restrict__ FrP)
{
    const int b = blockIdx.x, t = threadIdx.x;
    if (b < 8)  { packW(We2, We2p, 128, b,      C2);       return; }
    if (b < 16) { packW(Wx1, Wx1p, 128, b - 8,  C2);       return; }
    if (b < 24) { packW(Wx2, Wx2p, 128, b - 16, C2);       return; }
    if (b < 28) { packW(Wtp, Wtpp,  64, b - 24, 0.03125f); return; } // 1/sqrt(U*V)
    if (b == 28) {
        // B-frags of We1 rows 0..7, K padded to 32, pre-scaled C1.
        #pragma unroll
        for (int h = 0; h < 2; ++h) {
            int tt = t + h * 256;
            int ct = tt >> 6, l = tt & 63, g = l >> 4, c = l & 15;
            bf16x8 v = {0,0,0,0,0,0,0,0};
            if (g == 0) {
                #pragma unroll
                for (int j = 0; j < 8; ++j)
                    v[j] = f2bf(We1[j * 128 + ct * 16 + c] * C1);
            }
            *(bf16x8*)(We1Lp + (size_t)tt * 8) = v;
        }
        return;
    }
    // ---- proj: 2 nodes per block, outputs pre-scaled by C1 ----
    __shared__ float sF[256];
    const int n = (b - 29) * 2 + (t >> 7), j = t & 127, hb = t & 128;
    sF[t] = feat[n * 128 + j];
    __syncthreads();
    float a = 0.f, bb = 0.f;
    #pragma unroll 8
    for (int k = 0; k < 128; ++k) {
        float f = sF[hb + k];
        a  = fmaf(f, We1[(8   + k) * 128 + j], a);
        bb = fmaf(f, We1[(136 + k) * 128 + j], bb);
    }
    FsP[n * 128 + j] = a * C1;
    FrP[n * 128 + j] = bb * C1;
}

// ---------------------------------------------------------------------------
// laundered B-fragment loader (anchors loads at the call site, defeats LICM)
// ---------------------------------------------------------------------------
__device__ __forceinline__ void loadBz(const short* __restrict__ p,
                                       bf16x8 (&B)[2][4], int w, int lane)
{
    int zz = 0; asm volatile("" : "+v"(zz));
    const bf16x8* p8 = (const bf16x8*)p;
    #pragma unroll
    for (int ctl = 0; ctl < 2; ++ctl)
        #pragma unroll
        for (int kt = 0; kt < 4; ++kt)
            B[ctl][kt] = p8[((w * 2 + ctl) * 4 + kt) * 64 + lane + zz];
}

// MFMA-only part of the 32x128 @ 128x128 layer (weights pre-scaled).
__device__ __forceinline__ void gemm_mfma(const short* sIn_, const bf16x8 (&B)[2][4],
                                          const int (&adrK)[4], f32x4 (&acc)[2][2])
{
    const char* sIn = (const char*)sIn_;
    const f32x4 z = {0.f, 0.f, 0.f, 0.f};
    acc[0][0] = z; acc[0][1] = z; acc[1][0] = z; acc[1][1] = z;
    __builtin_amdgcn_s_setprio(1);
    #pragma unroll
    for (int kt = 0; kt < 4; ++kt) {
        bf16x8 a0 = *(const bf16x8*)(sIn + adrK[kt]);
        bf16x8 a1 = *(const bf16x8*)(sIn + adrK[kt] + 16 * SPB);
        acc[0][0] = MFMA16(a0, B[0][kt], acc[0][0], 0, 0, 0);
        acc[0][1] = MFMA16(a0, B[1][kt], acc[0][1], 0, 0, 0);
        acc[1][0] = MFMA16(a1, B[0][kt], acc[1][0], 0, 0, 0);
        acc[1][1] = MFMA16(a1, B[1][kt], acc[1][1], 0, 0, 0);
    }
    __builtin_amdgcn_s_setprio(0);
}

// epilogue: pure silu -> bf16 (cvt_pk) scatter into LDS (optionally keep fp32)
template<bool KEEP>
__device__ __forceinline__ void epi_store(const f32x4 (&acc)[2][2], short* sOut_,
                                          const int (&wAdr)[2][4], f32x4 (&keep)[2][2])
{
    char* sOut = (char*)sOut_;
    #pragma unroll
    for (int rt = 0; rt < 2; ++rt)
        #pragma unroll
        for (int ctl = 0; ctl < 2; ++ctl) {
            float v0 = silu_f(acc[rt][ctl][0]);
            float v1 = silu_f(acc[rt][ctl][1]);
            float v2 = silu_f(acc[rt][ctl][2]);
            float v3 = silu_f(acc[rt][ctl][3]);
            if (KEEP) {
                keep[rt][ctl][0] = v0; keep[rt][ctl][1] = v1;
                keep[rt][ctl][2] = v2; keep[rt][ctl][3] = v3;
            }
            unsigned p01, p23;
            CVT_PK(p01, v0, v1);
            CVT_PK(p23, v2, v3);
            char* o = sOut + rt * 16 * SPB;
            *(short*)(o + wAdr[ctl][0]) = (short)(p01 & 0xFFFFu);
            *(short*)(o + wAdr[ctl][1]) = (short)(p01 >> 16);
            *(short*)(o + wAdr[ctl][2]) = (short)(p23 & 0xFFFFu);
            *(short*)(o + wAdr[ctl][3]) = (short)(p23 >> 16);
        }
}

// ---------------------------------------------------------------------------
// k_edge: one block per (sender, half); 8 chunks of 32 receivers.
// R14 structure + pre-packed bf16 lens (L1 A-frag = direct b128 load).
// ---------------------------------------------------------------------------
__global__ __launch_bounds__(256, 4)
void k_edge(const float* __restrict__ pos,
            const float* __restrict__ Winf,
            const float* __restrict__ FsP,
            const float* __restrict__ FrP,
            const short* __restrict__ We1Lp,
            const short* __restrict__ We2p,
            const short* __restrict__ Wx1p,
            const short* __restrict__ Wx2p,
            const short* __restrict__ Wtpp,
            float* __restrict__ MI2,
            float* __restrict__ VEC2)
{
    __shared__ __align__(16) short sX[CH * (SPB / 2)];   // ping, padded rows
    __shared__ __align__(16) short sY[CH * (SPB / 2)];   // pong
    __shared__ __align__(16) float sLS[CH * NV * 4];     // (sh.xyz,len), v-swizzled
    __shared__ __align__(16) short sLen[CH * NV];        // bf16 lens, A-frag order
    __shared__ float sWinf[8 * 17];
    __shared__ float sPosS[24];
    __shared__ float sE[CH];
    __shared__ float sVp[4 * 24];

    const int bid = blockIdx.x;
    const int s = bid >> 1, half = bid & 1;
    const int t = threadIdx.x;
    const int lane = t & 63, w = t >> 6;
    const int rl = lane & 15, kg = lane >> 4;

    // ---- per-thread constant LDS byte addresses (linear, padded stride) ----
    int adrK[4];
    #pragma unroll
    for (int kt = 0; kt < 4; ++kt) adrK[kt] = rl * SPB + kg * 16 + kt * 64;
    int wAdr[2][4];
    #pragma unroll
    for (int ctl = 0; ctl < 2; ++ctl)
        #pragma unroll
        for (int jj = 0; jj < 4; ++jj) {
            int r = kg * 4 + jj;
            wAdr[ctl][jj] = r * SPB + w * 64 + ctl * 32 + 2 * rl;
        }
    const int colg0 = w * 32 + rl, colg1 = colg0 + 16;
    const int er = t >> 3, eo = t & 7;
    const int eAdr0 = er * SPB + eo * 32;
    const int eAdr1 = eAdr0 + 16;
    const int vv = w * 2 + (rl >> 3);

    if (t < 128) sWinf[(t >> 4) * 17 + (t & 15)] = Winf[t];
    if (t < 24)  sPosS[t] = pos[s * 24 + t];

    const float fs0 = FsP[s * 128 + colg0];   // pre-scaled C1
    const float fs1 = FsP[s * 128 + colg1];

    float miacc0 = 0.f, miacc1 = 0.f;
    float vax = 0.f, vay = 0.f, vaz = 0.f;
    __syncthreads();                                              // B0

    for (int c = 0; c < NCHH; ++c) {
        const int r0 = (half * NCHH + c) * CH;

        // ==== chunk-top issue: We2 frags + We1L frags + FrP->C-operand ====
        bf16x8 Bw[2][4];
        loadBz(We2p, Bw, w, lane);
        bf16x8 bL0, bL1;
        {
            int zz = 0; asm volatile("" : "+v"(zz));
            const bf16x8* pL = (const bf16x8*)We1Lp;
            bL0 = pL[(w * 2 + 0) * 64 + lane + zz];
            bL1 = pL[(w * 2 + 1) * 64 + lane + zz];
        }
        f32x4 cIn[2][2];
        {
            int zz = 0; asm volatile("" : "+v"(zz));
            #pragma unroll
            for (int rt = 0; rt < 2; ++rt)
                #pragma unroll
                for (int jj = 0; jj < 4; ++jj) {
                    const float* fp = FrP + (size_t)(r0 + rt * 16 + kg * 4 + jj) * 128 + zz;
                    cIn[rt][0][jj] = fp[colg0] + fs0;   // acc-init = fr' + fs'
                    cIn[rt][1][jj] = fp[colg1] + fs1;
                }
        }

        // ---- ph0: lengths + sh1 -> sLS; bf16 len -> sLen (A-frag order) ----
        {
            int r = t >> 3, v = t & 7;
            const float* pr = pos + (size_t)(r0 + r) * 24 + v * 3;
            float dx = sPosS[v * 3 + 0] - pr[0];
            float dy = sPosS[v * 3 + 1] - pr[1];
            float dz = sPosS[v * 3 + 2] - pr[2];
            float sq = fmaxf(dx * dx + dy * dy + dz * dz, 1e-20f);
            float rs = __builtin_amdgcn_rsqf(sq);
            float len = sq * rs;                      // = sqrt(sq); r==s -> sh1=0
            float inv = SQRT3 * rs;
            f32x4 o; o[0] = dx * inv; o[1] = dy * inv; o[2] = dz * inv; o[3] = len;
            *(f32x4*)(sLS + (r * 8 + (v ^ (r & 7))) * 4) = o;
            unsigned lp; CVT_PK(lp, len, len);
            sLen[r * 8 + v] = (short)lp;              // row-major 16B rows
        }
        __syncthreads();                                          // B1

        // ---- L1: lens @ We1L' with C-operand = fr'+fs'; pure-silu epi -> sX ----
        {
            bf16x8 aL0 = {0,0,0,0,0,0,0,0}, aL1 = {0,0,0,0,0,0,0,0};
            if (kg == 0) {
                aL0 = *(const bf16x8*)(sLen + rl * 8);          // 16B row, conflict-free
                aL1 = *(const bf16x8*)(sLen + (rl + 16) * 8);
            }
            f32x4 aP[2][2];
            aP[0][0] = MFMA16(aL0, bL0, cIn[0][0], 0, 0, 0);
            aP[0][1] = MFMA16(aL0, bL1, cIn[0][1], 0, 0, 0);
            aP[1][0] = MFMA16(aL1, bL0, cIn[1][0], 0, 0, 0);
            aP[1][1] = MFMA16(aL1, bL1, cIn[1][1], 0, 0, 0);
            f32x4 dummy[2][2];
            epi_store<false>(aP, sX, wAdr, dummy);
        }
        __syncthreads();                                          // B2

        // ---- L2: m_ij = silu(a1 @ We2') -> sY ; Wx1 issued under epilogue ----
        f32x4 acc[2][2];
        f32x4 keepM[2][2];
        gemm_mfma(sX, Bw, adrK, acc);          // consumes We2 (Bw regs die)
        bf16x8 Bn[2][4];
        loadBz(Wx1p, Bn, w, lane);             // Wx1 in flight: epi + e-phase
        epi_store<true>(acc, sY, wAdr, keepM);
        __syncthreads();                                          // B3

        // ---- e[r] = sigmoid(C2 * m_ij . Winf) ----
        {
            const char* sYc = (const char*)sY;
            uint4 m0 = *(const uint4*)(sYc + eAdr0);
            uint4 m1 = *(const uint4*)(sYc + eAdr1);
            const unsigned mu[8] = {m0.x, m0.y, m0.z, m0.w, m1.x, m1.y, m1.z, m1.w};
            float d = 0.f;
            #pragma unroll
            for (int q = 0; q < 8; ++q) {
                d = fmaf(bflo(mu[q]), sWinf[eo * 17 + 2 * q],     d);
                d = fmaf(bfhi(mu[q]), sWinf[eo * 17 + 2 * q + 1], d);
            }
            d += __shfl_xor(d, 1); d += __shfl_xor(d, 2); d += __shfl_xor(d, 4);
            if (eo == 0) sE[er] = (r0 + er == s) ? 0.f : sigm_f(d * C2);
        }
        __syncthreads();                                          // B4

        // ---- m_i accumulation from registers ----
        #pragma unroll
        for (int rt = 0; rt < 2; ++rt)
            #pragma unroll
            for (int jj = 0; jj < 4; ++jj) {
                float e = sE[rt * 16 + kg * 4 + jj];
                miacc0 = fmaf(keepM[rt][0][jj], e, miacc0);
                miacc1 = fmaf(keepM[rt][1][jj], e, miacc1);
            }

        // ---- L3: phi_x layer 1 ; Wx2 issued under epilogue ----
        gemm_mfma(sY, Bn, adrK, acc);          // consumes Wx1
        loadBz(Wx2p, Bw, w, lane);             // Wx2 in flight: epi + barrier
        epi_store<false>(acc, sX, wAdr, keepM);
        __syncthreads();                                          // B5

        // ---- L4: phi_x layer 2 ; Wtp issued under epilogue ----
        gemm_mfma(sX, Bw, adrK, acc);          // consumes Wx2
        bf16x8 Bt[4];
        {
            int zz = 0; asm volatile("" : "+v"(zz));
            const bf16x8* p8 = (const bf16x8*)Wtpp;
            #pragma unroll
            for (int kt = 0; kt < 4; ++kt) Bt[kt] = p8[(w * 4 + kt) * 64 + lane + zz];
        }
        epi_store<false>(acc, sY, wAdr, keepM);
        __syncthreads();                                          // B6

        // ---- TP gemm (Wtp' includes 1/32) + vec acc from regs ----
        {
            const f32x4 z = {0.f, 0.f, 0.f, 0.f};
            f32x4 acc0 = z, acc1 = z;
            const char* sYc = (const char*)sY;
            __builtin_amdgcn_s_setprio(1);
            #pragma unroll
            for (int kt = 0; kt < 4; ++kt) {
                bf16x8 a0 = *(const bf16x8*)(sYc + adrK[kt]);
                bf16x8 a1 = *(const bf16x8*)(sYc + adrK[kt] + 16 * SPB);
                acc0 = MFMA16(a0, Bt[kt], acc0, 0, 0, 0);
                acc1 = MFMA16(a1, Bt[kt], acc1, 0, 0, 0);
            }
            __builtin_amdgcn_s_setprio(0);
            #pragma unroll
            for (int rt = 0; rt < 2; ++rt)
                #pragma unroll
                for (int jj = 0; jj < 4; ++jj) {
                    int row = rt * 16 + kg * 4 + jj;
                    const f32x4 sh = *(const f32x4*)(sLS + (row * 8 + (vv ^ (row & 7))) * 4);
                    float g = rt ? acc1[jj] : acc0[jj];
                    vax = fmaf(g, sh[0], vax);
                    vay = fmaf(g, sh[1], vay);
                    vaz = fmaf(g, sh[2], vaz);
                }
        }
        __syncthreads();                                          // B7
    }

    // ---- epilogue: m_i reduce over row-groups ----
    miacc0 += __shfl_xor(miacc0, 16); miacc0 += __shfl_xor(miacc0, 32);
    miacc1 += __shfl_xor(miacc1, 16); miacc1 += __shfl_xor(miacc1, 32);
    if (lane < 16) {
        float* mo = MI2 + (size_t)(half * NN + s) * 128;
        mo[w * 32 + lane]      = miacc0;
        mo[w * 32 + 16 + lane] = miacc1;
    }
    // ---- vec reduce (1/32 folded into Wtpp) ----
    vax += __shfl_xor(vax, 8);  vay += __shfl_xor(vay, 8);  vaz += __shfl_xor(vaz, 8);
    vax += __shfl_xor(vax, 16); vay += __shfl_xor(vay, 16); vaz += __shfl_xor(vaz, 16);
    vax += __shfl_xor(vax, 32); vay += __shfl_xor(vay, 32); vaz += __shfl_xor(vaz, 32);
    if ((lane & 56) == 0) {
        float* vp = sVp + w * 24 + lane * 3;
        vp[0] = vax; vp[1] = vay; vp[2] = vaz;
    }
    __syncthreads();
    if (t < 24) {
        float sum = sVp[t] + sVp[24 + t] + sVp[48 + t] + sVp[72 + t];
        VEC2[(size_t)(half * NN + s) * 24 + t] = sum;
    }
}

// ---------------------------------------------------------------------------
// k_node: 2 nodes/block; h-MLP + residual + position update (sums 2 halves).
// ---------------------------------------------------------------------------
__global__ __launch_bounds__(256)
void k_node(const float* __restrict__ pos, const float* __restrict__ feat,
            const float* __restrict__ Wh1, const float* __restrict__ Wh2,
            const float* __restrict__ Wh3,
            const float* __restrict__ MI2, const float* __restrict__ VEC2,
            float* __restrict__ outPos, float* __restrict__ outFeat)
{
    __shared__ float sMi[256], sF[256], sH[256];
    const int t = threadIdx.x;
    const int n = blockIdx.x * 2 + (t >> 7), j = t & 127, hb = t & 128;
    sMi[t] = MI2[n * 128 + j] + MI2[NN * 128 + n * 128 + j];
    sF[t]  = feat[n * 128 + j];
    __syncthreads();
    float a = 0.f;
    #pragma unroll 8
    for (int k = 0; k < 128; ++k) a = fmaf(sMi[hb + k], Wh1[k * 128 + j], a);
    #pragma unroll 8
    for (int k = 0; k < 128; ++k) a = fmaf(sF[hb + k], Wh1[(128 + k) * 128 + j], a);
    a = silu_f(a * 0.0625f);            // 1/sqrt(256)
    sH[t] = a;
    __syncthreads();
    float b = 0.f;
    #pragma unroll 8
    for (int k = 0; k < 128; ++k) b = fmaf(sH[hb + k], Wh2[k * 128 + j], b);
    b = silu_f(b * C2);
    sMi[t] = b;
    __syncthreads();
    float cc = 0.f;
    #pragma unroll 8
    for (int k = 0; k < 128; ++k) cc = fmaf(sMi[hb + k], Wh3[k * 128 + j], cc);
    outFeat[n * 128 + j] = cc * C2 + sF[t];
    if (j < 24) outPos[n * 24 + j] = pos[n * 24 + j]
                                   + VEC2[n * 24 + j] + VEC2[NN * 24 + n * 24 + j];
}

// ---------------------------------------------------------------------------
extern "C" void kernel_launch(void* const* d_in, const int* in_sizes, int n_in,
                              void* d_out, int out_size, void* d_ws, size_t ws_size,
                              hipStream_t stream) {
    const float* pos  = (const float*)d_in[0];
    const float* feat = (const float*)d_in[1];
    const float* We1  = (const float*)d_in[2];
    const float* We2  = (const float*)d_in[3];
    const float* Wx1  = (const float*)d_in[4];
    const float* Wx2  = (const float*)d_in[5];
    const float* Winf = (const float*)d_in[6];
    const float* Wtp  = (const float*)d_in[7];
    const float* Wh1  = (const float*)d_in[8];
    const float* Wh2  = (const float*)d_in[9];
    const float* Wh3  = (const float*)d_in[10];

    float* outPos  = (float*)d_out;              // [512*8*3]
    float* outFeat = (float*)d_out + NN * 24;    // [512*128]

    float* ws   = (float*)d_ws;
    float* FsP  = ws;                   // 65536 floats (pre-scaled C1)
    float* FrP  = ws + 65536;           // 65536 (pre-scaled C1)
    float* MI2  = ws + 131072;          // 2*65536
    float* VEC2 = ws + 262144;          // 2*12288
    short* wpack = (short*)(ws + 286720);
    short* We2p  = wpack;               // 16384 shorts (pre-scaled C2)
    short* Wx1p  = wpack + 16384;       // 16384 (C2)
    short* Wx2p  = wpack + 32768;       // 16384 (C2)
    short* Wtpp  = wpack + 49152;       // 8192  (1/32)
    short* We1Lp = wpack + 57344;       // 4096  (C1)

    k_packall<<<dim3(285), dim3(256), 0, stream>>>(We2, Wx1, Wx2, Wtp, We1, feat,
                                                   We2p, Wx1p, Wx2p, Wtpp, We1Lp,
                                                   FsP, FrP);
    k_edge<<<dim3(2 * NN), dim3(256), 0, stream>>>(pos, Winf, FsP, FrP, We1Lp,
                                                   We2p, Wx1p, Wx2p, Wtpp, MI2, VEC2);
    k_node<<<dim3(NN / 2), dim3(256), 0, stream>>>(pos, feat, Wh1, Wh2, Wh3, MI2, VEC2,
                                                   outPos, outFeat);
}

// Round 16
// 88.173 us; speedup vs baseline: 1.5675x; 1.0313x over previous
//
#include <hip/hip_runtime.h>
#include <math.h>

#define NN   512
#define NV   8
#define CH   32      // receivers per chunk
#define NCHH 8       // chunks per half-block (2 blocks per sender)
#define SPB  272     // activation LDS row stride in BYTES (17*16: bank-phase pad)

#define C1 0.06154574548966636f   // 1/sqrt(264)
#define C2 0.08838834764831845f   // 1/sqrt(128)
#define SQRT3 1.7320508075688772f

typedef __attribute__((ext_vector_type(8))) short bf16x8;   // 8 bf16 = 4 VGPRs
typedef __attribute__((ext_vector_type(4))) float f32x4;

#define MFMA16 __builtin_amdgcn_mfma_f32_16x16x32_bf16
#define CVT_PK(dst, a, b) asm("v_cvt_pk_bf16_f32 %0, %1, %2" : "=v"(dst) : "v"(a), "v"(b))

__device__ __forceinline__ float silu_f(float x) {
    float e = __builtin_amdgcn_exp2f(x * -1.442695041f);
    return x * __builtin_amdgcn_rcpf(1.0f + e);
}
__device__ __forceinline__ float sigm_f(float x) {
    float e = __builtin_amdgcn_exp2f(x * -1.442695041f);
    return __builtin_amdgcn_rcpf(1.0f + e);
}
__device__ __forceinline__ short f2bf(float f) {
    unsigned u = __builtin_bit_cast(unsigned, f);
    u = (u + 0x7FFFu + ((u >> 16) & 1u)) >> 16;
    return (short)u;
}
__device__ __forceinline__ float bfhi(unsigned u) {
    return __builtin_bit_cast(float, u & 0xFFFF0000u);
}
__device__ __forceinline__ float bflo(unsigned u) {
    return __builtin_bit_cast(float, u << 16);
}

// ---------------------------------------------------------------------------
// k_packall: all weight packing + proj in ONE launch; weights PRE-SCALED.
// Frag (ct,kt), lane l, elem j holds W[32kt + (l>>4)*8 + j][16ct + (l&15)].
// ---------------------------------------------------------------------------
__device__ __forceinline__ void packW(const float* __restrict__ W,
                                      short* __restrict__ out, int ncols, int ct,
                                      float scale)
{
    int t = threadIdx.x;
    int lane = t & 63, kt = (t >> 6) & 3;
    int g = lane >> 4, c = lane & 15;
    bf16x8 v;
    #pragma unroll
    for (int j = 0; j < 8; ++j)
        v[j] = f2bf(W[(kt * 32 + g * 8 + j) * ncols + ct * 16 + c] * scale);
    *(bf16x8*)(out + (size_t)(ct * 256 + t) * 8) = v;
}

__global__ __launch_bounds__(256)
void k_packall(const float* __restrict__ We2, const float* __restrict__ Wx1,
               const float* __restrict__ Wx2, const float* __restrict__ Wtp,
               const float* __restrict__ We1, const float* __restrict__ feat,
               short* __restrict__ We2p, short* __restrict__ Wx1p,
               short* __restrict__ Wx2p, short* __restrict__ Wtpp,
               short* __restrict__ We1Lp,
               float* __restrict__ FsP, float* __restrict__ FrP)
{
    const int b = blockIdx.x, t = threadIdx.x;
    if (b < 8)  { packW(We2, We2p, 128, b,      C2);       return; }
    if (b < 16) { packW(Wx1, Wx1p, 128, b - 8,  C2);       return; }
    if (b < 24) { packW(Wx2, Wx2p, 128, b - 16, C2);       return; }
    if (b < 28) { packW(Wtp, Wtpp,  64, b - 24, 0.03125f); return; } // 1/sqrt(U*V)
    if (b == 28) {
        // B-frags of We1 rows 0..7, K padded to 32, pre-scaled C1.
        #pragma unroll
        for (int h = 0; h < 2; ++h) {
            int tt = t + h * 256;
            int ct = tt >> 6, l = tt & 63, g = l >> 4, c = l & 15;
            bf16x8 v = {0,0,0,0,0,0,0,0};
            if (g == 0) {
                #pragma unroll
                for (int j = 0; j < 8; ++j)
                    v[j] = f2bf(We1[j * 128 + ct * 16 + c] * C1);
            }
            *(bf16x8*)(We1Lp + (size_t)tt * 8) = v;
        }
        return;
    }
    // ---- proj: 2 nodes per block, outputs pre-scaled by C1 ----
    __shared__ float sF[256];
    const int n = (b - 29) * 2 + (t >> 7), j = t & 127, hb = t & 128;
    sF[t] = feat[n * 128 + j];
    __syncthreads();
    float a = 0.f, bb = 0.f;
    #pragma unroll 8
    for (int k = 0; k < 128; ++k) {
        float f = sF[hb + k];
        a  = fmaf(f, We1[(8   + k) * 128 + j], a);
        bb = fmaf(f, We1[(136 + k) * 128 + j], bb);
    }
    FsP[n * 128 + j] = a * C1;
    FrP[n * 128 + j] = bb * C1;
}

// ---------------------------------------------------------------------------
// B-fragment loader via uniform base + 32-bit voffset + imm deltas.
// v0 covers ctl=0 (kt imm 0..3072), v1 = v0+4096 covers ctl=1.
// ---------------------------------------------------------------------------
__device__ __forceinline__ void loadB_off(const short* __restrict__ p,
                                          bf16x8 (&B)[2][4],
                                          unsigned v0, unsigned v1)
{
    const char* pc = (const char*)p;
    #pragma unroll
    for (int kt = 0; kt < 4; ++kt) {
        B[0][kt] = *(const bf16x8*)(pc + v0 + kt * 1024);
        B[1][kt] = *(const bf16x8*)(pc + v1 + kt * 1024);
    }
}

// MFMA-only part of the 32x128 @ 128x128 layer (weights pre-scaled).
__device__ __forceinline__ void gemm_mfma(const short* sIn_, const bf16x8 (&B)[2][4],
                                          const int (&adrK)[4], f32x4 (&acc)[2][2])
{
    const char* sIn = (const char*)sIn_;
    const f32x4 z = {0.f, 0.f, 0.f, 0.f};
    acc[0][0] = z; acc[0][1] = z; acc[1][0] = z; acc[1][1] = z;
    __builtin_amdgcn_s_setprio(1);
    #pragma unroll
    for (int kt = 0; kt < 4; ++kt) {
        bf16x8 a0 = *(const bf16x8*)(sIn + adrK[kt]);
        bf16x8 a1 = *(const bf16x8*)(sIn + adrK[kt] + 16 * SPB);
        acc[0][0] = MFMA16(a0, B[0][kt], acc[0][0], 0, 0, 0);
        acc[0][1] = MFMA16(a0, B[1][kt], acc[0][1], 0, 0, 0);
        acc[1][0] = MFMA16(a1, B[0][kt], acc[1][0], 0, 0, 0);
        acc[1][1] = MFMA16(a1, B[1][kt], acc[1][1], 0, 0, 0);
    }
    __builtin_amdgcn_s_setprio(0);
}

// epilogue: pure silu -> bf16 (cvt_pk) scatter into LDS (optionally keep fp32)
template<bool KEEP>
__device__ __forceinline__ void epi_store(const f32x4 (&acc)[2][2], short* sOut_,
                                          const int (&wAdr)[2][4], f32x4 (&keep)[2][2])
{
    char* sOut = (char*)sOut_;
    #pragma unroll
    for (int rt = 0; rt < 2; ++rt)
        #pragma unroll
        for (int ctl = 0; ctl < 2; ++ctl) {
            float v0 = silu_f(acc[rt][ctl][0]);
            float v1 = silu_f(acc[rt][ctl][1]);
            float v2 = silu_f(acc[rt][ctl][2]);
            float v3 = silu_f(acc[rt][ctl][3]);
            if (KEEP) {
                keep[rt][ctl][0] = v0; keep[rt][ctl][1] = v1;
                keep[rt][ctl][2] = v2; keep[rt][ctl][3] = v3;
            }
            unsigned p01, p23;
            CVT_PK(p01, v0, v1);
            CVT_PK(p23, v2, v3);
            char* o = sOut + rt * 16 * SPB;
            *(short*)(o + wAdr[ctl][0]) = (short)(p01 & 0xFFFFu);
            *(short*)(o + wAdr[ctl][1]) = (short)(p01 >> 16);
            *(short*)(o + wAdr[ctl][2]) = (short)(p23 & 0xFFFFu);
            *(short*)(o + wAdr[ctl][3]) = (short)(p23 >> 16);
        }
}

// ---------------------------------------------------------------------------
// k_edge: one block per (sender, half); 8 chunks of 32 receivers.
// R15 structure; global loads via uniform-base + voffset (imm-folded deltas),
// laundered once per chunk on the voffsets only.
// ---------------------------------------------------------------------------
__global__ __launch_bounds__(256, 4)
void k_edge(const float* __restrict__ pos,
            const float* __restrict__ Winf,
            const float* __restrict__ FsP,
            const float* __restrict__ FrP,
            const short* __restrict__ We1Lp,
            const short* __restrict__ We2p,
            const short* __restrict__ Wx1p,
            const short* __restrict__ Wx2p,
            const short* __restrict__ Wtpp,
            float* __restrict__ MI2,
            float* __restrict__ VEC2)
{
    __shared__ __align__(16) short sX[CH * (SPB / 2)];   // ping, padded rows
    __shared__ __align__(16) short sY[CH * (SPB / 2)];   // pong
    __shared__ __align__(16) float sLS[CH * NV * 4];     // (sh.xyz,len), v-swizzled
    __shared__ __align__(16) short sLen[CH * NV];        // bf16 lens, A-frag order
    __shared__ float sWinf[8 * 17];
    __shared__ float sPosS[24];
    __shared__ float sE[CH];
    __shared__ float sVp[4 * 24];

    const int bid = blockIdx.x;
    const int s = bid >> 1, half = bid & 1;
    const int t = threadIdx.x;
    const int lane = t & 63, w = t >> 6;
    const int rl = lane & 15, kg = lane >> 4;

    // ---- per-thread constant LDS byte addresses (linear, padded stride) ----
    int adrK[4];
    #pragma unroll
    for (int kt = 0; kt < 4; ++kt) adrK[kt] = rl * SPB + kg * 16 + kt * 64;
    int wAdr[2][4];
    #pragma unroll
    for (int ctl = 0; ctl < 2; ++ctl)
        #pragma unroll
        for (int jj = 0; jj < 4; ++jj) {
            int r = kg * 4 + jj;
            wAdr[ctl][jj] = r * SPB + w * 64 + ctl * 32 + 2 * rl;
        }
    const int colg0 = w * 32 + rl, colg1 = colg0 + 16;
    const int er = t >> 3, eo = t & 7;
    const int eAdr0 = er * SPB + eo * 32;
    const int eAdr1 = eAdr0 + 16;
    const int vv = w * 2 + (rl >> 3);

    // ---- persistent 32-bit voffsets for streamed global loads ----
    unsigned vW0 = (unsigned)(w * 8 * 1024 + lane * 16);     // ctl=0 frags
    unsigned vW1 = vW0 + 4096;                               // ctl=1 frags
    unsigned vT  = (unsigned)(w * 4 * 1024 + lane * 16);     // Wtp frags
    unsigned vL  = (unsigned)(w * 2 * 1024 + lane * 16);     // We1L frags
    unsigned vF  = (unsigned)(((half * NCHH) * CH + kg * 4) * 512 + colg0 * 4); // FrP rt=0
    unsigned vP  = (unsigned)(((half * NCHH) * CH + (t >> 3)) * 96 + (t & 7) * 12);

    if (t < 128) sWinf[(t >> 4) * 17 + (t & 15)] = Winf[t];
    if (t < 24)  sPosS[t] = pos[s * 24 + t];

    const float fs0 = FsP[s * 128 + colg0];   // pre-scaled C1
    const float fs1 = FsP[s * 128 + colg1];

    float miacc0 = 0.f, miacc1 = 0.f;
    float vax = 0.f, vay = 0.f, vaz = 0.f;
    __syncthreads();                                              // B0

    for (int c = 0; c < NCHH; ++c) {
        const int r0 = (half * NCHH + c) * CH;

        // anchor the voffsets (1 instr) so loads re-issue each chunk
        asm volatile("" : "+v"(vW0), "+v"(vW1), "+v"(vT), "+v"(vL), "+v"(vF), "+v"(vP));

        // ==== chunk-top issue: We2 frags + We1L frags + FrP->C-operand ====
        bf16x8 Bw[2][4];
        loadB_off(We2p, Bw, vW0, vW1);
        bf16x8 bL0, bL1;
        {
            const char* pc = (const char*)We1Lp;
            bL0 = *(const bf16x8*)(pc + vL);
            bL1 = *(const bf16x8*)(pc + vL + 1024);
        }
        f32x4 cIn[2][2];
        {
            const char* fp = (const char*)FrP;
            const unsigned vF1 = vF + 8192;
            #pragma unroll
            for (int jj = 0; jj < 4; ++jj) {
                cIn[0][0][jj] = *(const float*)(fp + vF  + jj * 512)      + fs0;
                cIn[0][1][jj] = *(const float*)(fp + vF  + jj * 512 + 64) + fs1;
                cIn[1][0][jj] = *(const float*)(fp + vF1 + jj * 512)      + fs0;
                cIn[1][1][jj] = *(const float*)(fp + vF1 + jj * 512 + 64) + fs1;
            }
            vF += 16384;
        }

        // ---- ph0: lengths + sh1 -> sLS; bf16 len -> sLen (A-frag order) ----
        {
            int r = t >> 3, v = t & 7;
            const char* pp = (const char*)pos;
            float dx = sPosS[v * 3 + 0] - *(const float*)(pp + vP);
            float dy = sPosS[v * 3 + 1] - *(const float*)(pp + vP + 4);
            float dz = sPosS[v * 3 + 2] - *(const float*)(pp + vP + 8);
            vP += 3072;
            float sq = fmaxf(dx * dx + dy * dy + dz * dz, 1e-20f);
            float rs = __builtin_amdgcn_rsqf(sq);
            float len = sq * rs;                      // = sqrt(sq); r==s -> sh1=0
            float inv = SQRT3 * rs;
            f32x4 o; o[0] = dx * inv; o[1] = dy * inv; o[2] = dz * inv; o[3] = len;
            *(f32x4*)(sLS + (r * 8 + (v ^ (r & 7))) * 4) = o;
            unsigned lp; CVT_PK(lp, len, len);
            sLen[r * 8 + v] = (short)lp;              // row-major 16B rows
        }
        __syncthreads();                                          // B1

        // ---- L1: lens @ We1L' with C-operand = fr'+fs'; pure-silu epi -> sX ----
        {
            bf16x8 aL0 = {0,0,0,0,0,0,0,0}, aL1 = {0,0,0,0,0,0,0,0};
            if (kg == 0) {
                aL0 = *(const bf16x8*)(sLen + rl * 8);          // 16B row, conflict-free
                aL1 = *(const bf16x8*)(sLen + (rl + 16) * 8);
            }
            f32x4 aP[2][2];
            aP[0][0] = MFMA16(aL0, bL0, cIn[0][0], 0, 0, 0);
            aP[0][1] = MFMA16(aL0, bL1, cIn[0][1], 0, 0, 0);
            aP[1][0] = MFMA16(aL1, bL0, cIn[1][0], 0, 0, 0);
            aP[1][1] = MFMA16(aL1, bL1, cIn[1][1], 0, 0, 0);
            f32x4 dummy[2][2];
            epi_store<false>(aP, sX, wAdr, dummy);
        }
        __syncthreads();                                          // B2

        // ---- L2: m_ij = silu(a1 @ We2') -> sY ; Wx1 issued under epilogue ----
        f32x4 acc[2][2];
        f32x4 keepM[2][2];
        gemm_mfma(sX, Bw, adrK, acc);          // consumes We2 (Bw regs die)
        bf16x8 Bn[2][4];
        loadB_off(Wx1p, Bn, vW0, vW1);         // Wx1 in flight: epi + e-phase
        epi_store<true>(acc, sY, wAdr, keepM);
        __syncthreads();                                          // B3

        // ---- e[r] = sigmoid(C2 * m_ij . Winf) ----
        {
            const char* sYc = (const char*)sY;
            uint4 m0 = *(const uint4*)(sYc + eAdr0);
            uint4 m1 = *(const uint4*)(sYc + eAdr1);
            const unsigned mu[8] = {m0.x, m0.y, m0.z, m0.w, m1.x, m1.y, m1.z, m1.w};
            float d = 0.f;
            #pragma unroll
            for (int q = 0; q < 8; ++q) {
                d = fmaf(bflo(mu[q]), sWinf[eo * 17 + 2 * q],     d);
                d = fmaf(bfhi(mu[q]), sWinf[eo * 17 + 2 * q + 1], d);
            }
            d += __shfl_xor(d, 1); d += __shfl_xor(d, 2); d += __shfl_xor(d, 4);
            if (eo == 0) sE[er] = (r0 + er == s) ? 0.f : sigm_f(d * C2);
        }
        __syncthreads();                                          // B4

        // ---- m_i accumulation from registers ----
        #pragma unroll
        for (int rt = 0; rt < 2; ++rt)
            #pragma unroll
            for (int jj = 0; jj < 4; ++jj) {
                float e = sE[rt * 16 + kg * 4 + jj];
                miacc0 = fmaf(keepM[rt][0][jj], e, miacc0);
                miacc1 = fmaf(keepM[rt][1][jj], e, miacc1);
            }

        // ---- L3: phi_x layer 1 ; Wx2 issued under epilogue ----
        gemm_mfma(sY, Bn, adrK, acc);          // consumes Wx1
        loadB_off(Wx2p, Bw, vW0, vW1);         // Wx2 in flight: epi + barrier
        epi_store<false>(acc, sX, wAdr, keepM);
        __syncthreads();                                          // B5

        // ---- L4: phi_x layer 2 ; Wtp issued under epilogue ----
        gemm_mfma(sX, Bw, adrK, acc);          // consumes Wx2
        bf16x8 Bt[4];
        {
            const char* pc = (const char*)Wtpp;
            #pragma unroll
            for (int kt = 0; kt < 4; ++kt)
                Bt[kt] = *(const bf16x8*)(pc + vT + kt * 1024);
        }
        epi_store<false>(acc, sY, wAdr, keepM);
        __syncthreads();                                          // B6

        // ---- TP gemm (Wtp' includes 1/32) + vec acc from regs ----
        {
            const f32x4 z = {0.f, 0.f, 0.f, 0.f};
            f32x4 acc0 = z, acc1 = z;
            const char* sYc = (const char*)sY;
            __builtin_amdgcn_s_setprio(1);
            #pragma unroll
            for (int kt = 0; kt < 4; ++kt) {
                bf16x8 a0 = *(const bf16x8*)(sYc + adrK[kt]);
                bf16x8 a1 = *(const bf16x8*)(sYc + adrK[kt] + 16 * SPB);
                acc0 = MFMA16(a0, Bt[kt], acc0, 0, 0, 0);
                acc1 = MFMA16(a1, Bt[kt], acc1, 0, 0, 0);
            }
            __builtin_amdgcn_s_setprio(0);
            #pragma unroll
            for (int rt = 0; rt < 2; ++rt)
                #pragma unroll
                for (int jj = 0; jj < 4; ++jj) {
                    int row = rt * 16 + kg * 4 + jj;
                    const f32x4 sh = *(const f32x4*)(sLS + (row * 8 + (vv ^ (row & 7))) * 4);
                    float g = rt ? acc1[jj] : acc0[jj];
                    vax = fmaf(g, sh[0], vax);
                    vay = fmaf(g, sh[1], vay);
                    vaz = fmaf(g, sh[2], vaz);
                }
        }
        __syncthreads();                                          // B7
    }

    // ---- epilogue: m_i reduce over row-groups ----
    miacc0 += __shfl_xor(miacc0, 16); miacc0 += __shfl_xor(miacc0, 32);
    miacc1 += __shfl_xor(miacc1, 16); miacc1 += __shfl_xor(miacc1, 32);
    if (lane < 16) {
        float* mo = MI2 + (size_t)(half * NN + s) * 128;
        mo[w * 32 + lane]      = miacc0;
        mo[w * 32 + 16 + lane] = miacc1;
    }
    // ---- vec reduce (1/32 folded into Wtpp) ----
    vax += __shfl_xor(vax, 8);  vay += __shfl_xor(vay, 8);  vaz += __shfl_xor(vaz, 8);
    vax += __shfl_xor(vax, 16); vay += __shfl_xor(vay, 16); vaz += __shfl_xor(vaz, 16);
    vax += __shfl_xor(vax, 32); vay += __shfl_xor(vay, 32); vaz += __shfl_xor(vaz, 32);
    if ((lane & 56) == 0) {
        float* vp = sVp + w * 24 + lane * 3;
        vp[0] = vax; vp[1] = vay; vp[2] = vaz;
    }
    __syncthreads();
    if (t < 24) {
        float sum = sVp[t] + sVp[24 + t] + sVp[48 + t] + sVp[72 + t];
        VEC2[(size_t)(half * NN + s) * 24 + t] = sum;
    }
}

// ---------------------------------------------------------------------------
// k_node: 2 nodes/block; h-MLP + residual + position update (sums 2 halves).
// ---------------------------------------------------------------------------
__global__ __launch_bounds__(256)
void k_node(const float* __restrict__ pos, const float* __restrict__ feat,
            const float* __restrict__ Wh1, const float* __restrict__ Wh2,
            const float* __restrict__ Wh3,
            const float* __restrict__ MI2, const float* __restrict__ VEC2,
            float* __restrict__ outPos, float* __restrict__ outFeat)
{
    __shared__ float sMi[256], sF[256], sH[256];
    const int t = threadIdx.x;
    const int n = blockIdx.x * 2 + (t >> 7), j = t & 127, hb = t & 128;
    sMi[t] = MI2[n * 128 + j] + MI2[NN * 128 + n * 128 + j];
    sF[t]  = feat[n * 128 + j];
    __syncthreads();
    float a = 0.f;
    #pragma unroll 8
    for (int k = 0; k < 128; ++k) a = fmaf(sMi[hb + k], Wh1[k * 128 + j], a);
    #pragma unroll 8
    for (int k = 0; k < 128; ++k) a = fmaf(sF[hb + k], Wh1[(128 + k) * 128 + j], a);
    a = silu_f(a * 0.0625f);            // 1/sqrt(256)
    sH[t] = a;
    __syncthreads();
    float b = 0.f;
    #pragma unroll 8
    for (int k = 0; k < 128; ++k) b = fmaf(sH[hb + k], Wh2[k * 128 + j], b);
    b = silu_f(b * C2);
    sMi[t] = b;
    __syncthreads();
    float cc = 0.f;
    #pragma unroll 8
    for (int k = 0; k < 128; ++k) cc = fmaf(sMi[hb + k], Wh3[k * 128 + j], cc);
    outFeat[n * 128 + j] = cc * C2 + sF[t];
    if (j < 24) outPos[n * 24 + j] = pos[n * 24 + j]
                                   + VEC2[n * 24 + j] + VEC2[NN * 24 + n * 24 + j];
}

// ---------------------------------------------------------------------------
extern "C" void kernel_launch(void* const* d_in, const int* in_sizes, int n_in,
                              void* d_out, int out_size, void* d_ws, size_t ws_size,
                              hipStream_t stream) {
    const float* pos  = (const float*)d_in[0];
    const float* feat = (const float*)d_in[1];
    const float* We1  = (const float*)d_in[2];
    const float* We2  = (const float*)d_in[3];
    const float* Wx1  = (const float*)d_in[4];
    const float* Wx2  = (const float*)d_in[5];
    const float* Winf = (const float*)d_in[6];
    const float* Wtp  = (const float*)d_in[7];
    const float* Wh1  = (const float*)d_in[8];
    const float* Wh2  = (const float*)d_in[9];
    const float* Wh3  = (const float*)d_in[10];

    float* outPos  = (float*)d_out;              // [512*8*3]
    float* outFeat = (float*)d_out + NN * 24;    // [512*128]

    float* ws   = (float*)d_ws;
    float* FsP  = ws;                   // 65536 floats (pre-scaled C1)
    float* FrP  = ws + 65536;           // 65536 (pre-scaled C1)
    float* MI2  = ws + 131072;          // 2*65536
    float* VEC2 = ws + 262144;          // 2*12288
    short* wpack = (short*)(ws + 286720);
    short* We2p  = wpack;               // 16384 shorts (pre-scaled C2)
    short* Wx1p  = wpack + 16384;       // 16384 (C2)
    short* Wx2p  = wpack + 32768;       // 16384 (C2)
    short* Wtpp  = wpack + 49152;       // 8192  (1/32)
    short* We1Lp = wpack + 57344;       // 4096  (C1)

    k_packall<<<dim3(285), dim3(256), 0, stream>>>(We2, Wx1, Wx2, Wtp, We1, feat,
                                                   We2p, Wx1p, Wx2p, Wtpp, We1Lp,
                                                   FsP, FrP);
    k_edge<<<dim3(2 * NN), dim3(256), 0, stream>>>(pos, Winf, FsP, FrP, We1Lp,
                                                   We2p, Wx1p, Wx2p, Wtpp, MI2, VEC2);
    k_node<<<dim3(NN / 2), dim3(256), 0, stream>>>(pos, feat, Wh1, Wh2, Wh3, MI2, VEC2,
                                                   outPos, outFeat);
}